// Round 2
// baseline (1663.683 us; speedup 1.0000x reference)
//
#include <hip/hip_runtime.h>
#include <math.h>

#define DIMX 512
#define HEADS 8
#define DHEAD 64
#define NBFX 256
#define FFD 2048
#define NBX 4
#define SEQ 8192
#define TOK (NBX*SEQ)     // 32768 tokens
#define NBH (NBX*HEADS)   // 32 (b,h) pairs
#define VROWS 80          // 64 v-dims + ones row(64) + zeros pad
#define NCHUNK 16         // ctx K-split chunks (512 tokens each)

typedef unsigned short u16;
typedef __attribute__((ext_vector_type(8))) short short8;
typedef __attribute__((ext_vector_type(4))) float f32x4;

__device__ __forceinline__ float bf2f(u16 x){ return __uint_as_float(((unsigned)x)<<16); }
__device__ __forceinline__ u16 f2bf(float f){
  unsigned u=__float_as_uint(f);
  return (u16)((u + 0x7FFFu + ((u>>16)&1u))>>16);
}
__device__ __forceinline__ void gload16(const void* g, void* l){
  __builtin_amdgcn_global_load_lds((const __attribute__((address_space(1))) void*)g,
                                   (__attribute__((address_space(3))) void*)l, 16, 0, 0);
}
// order-preserving float<->uint map for atomicMax on floats
__device__ __forceinline__ unsigned fenc(float f){
  unsigned b=__float_as_uint(f); return (b&0x80000000u)? ~b : (b|0x80000000u);
}
__device__ __forceinline__ float fdec(unsigned u){
  return __uint_as_float((u&0x80000000u)? (u&0x7FFFFFFFu) : ~u);
}

// ---------------- prep / elementwise ----------------
__global__ void copy_f32(const float4* __restrict__ s, float4* __restrict__ d, int n4){
  int i=blockIdx.x*blockDim.x+threadIdx.x;
  if(i<n4) d[i]=s[i];
}
__global__ void conv_proj(const float* __restrict__ p, u16* __restrict__ o, int n){
  int i=blockIdx.x*blockDim.x+threadIdx.x;
  if(i<n) o[i]=f2bf(p[i]*0.35355339059327373f); // fold d^-0.25 into proj
}
// src fp32 [K][Ncol] -> dst bf16 [Ncol][K] (transposed)
__global__ void convT(const float* __restrict__ src, u16* __restrict__ dst, int K, int Ncol){
  __shared__ float t[32][33];
  int k0=blockIdx.y*32, n0=blockIdx.x*32;
  int tx=threadIdx.x, ty=threadIdx.y;
  for(int i=ty;i<32;i+=8) t[i][tx]=src[(size_t)(k0+i)*Ncol + n0+tx];
  __syncthreads();
  for(int i=ty;i<32;i+=8) dst[(size_t)(n0+i)*K + k0+tx]=f2bf(t[tx][i]);
}
// vT rows 64..79: row 64 = ones (k_sum trick), 65..79 = zeros
__global__ void fill_vt(u16* __restrict__ vt){
  int i=blockIdx.x*blockDim.x+threadIdx.x; // < NBH*16*SEQ = 2^22
  int n=i&(SEQ-1); int r=(i>>13)&15; int bh=i>>17;
  vt[((size_t)bh*VROWS + 64 + r)*SEQ + n] = (r==0)? (u16)0x3F80 : (u16)0;
}
__global__ void kinit(unsigned* k){ if(threadIdx.x<NBH) k[threadIdx.x]=0u; }

__global__ __launch_bounds__(256) void ln_k(const float* __restrict__ x, const float* __restrict__ g,
                                            const float* __restrict__ b, u16* __restrict__ y){
  int row=blockIdx.x, t=threadIdx.x;
  const float* xr=x+(size_t)row*DIMX;
  float2 v=*(const float2*)&xr[t*2];
  float s=v.x+v.y;
  #pragma unroll
  for(int m=1;m<64;m<<=1) s+=__shfl_xor(s,m);
  __shared__ float red[8];
  if((t&63)==0) red[t>>6]=s;
  __syncthreads();
  float mean=(red[0]+red[1]+red[2]+red[3])*(1.0f/DIMX);
  float dx=v.x-mean, dy=v.y-mean;
  float s2=dx*dx+dy*dy;
  #pragma unroll
  for(int m=1;m<64;m<<=1) s2+=__shfl_xor(s2,m);
  if((t&63)==0) red[4+(t>>6)]=s2;
  __syncthreads();
  float var=(red[4]+red[5]+red[6]+red[7])*(1.0f/DIMX);
  float rs=rsqrtf(var+1e-5f);
  u16* yr=y+(size_t)row*DIMX;
  yr[t*2  ]=f2bf(dx*rs*g[t*2  ]+b[t*2  ]);
  yr[t*2+1]=f2bf(dy*rs*g[t*2+1]+b[t*2+1]);
}

// ---------------- generic bf16 MFMA GEMM: C = A[M,K] * Bt[N,K]^T + bias ----------------
// EPI 0: bf16 out; 1: fp32 out += (residual in-place); 2: gelu->bf16; 3: V-transposed bf16 out
template<int EPI>
__global__ __launch_bounds__(256) void gemm_bt(const u16* __restrict__ A, const u16* __restrict__ Bt,
                                               const float* __restrict__ bias, void* __restrict__ outp,
                                               int M, int Ncol, int K){
  __shared__ u16 As[128*32];
  __shared__ u16 Bs[128*32];
  const int m0=blockIdx.y*128, n0=blockIdx.x*128;
  const int tid=threadIdx.x, wv=tid>>6, ln=tid&63;
  const int wr=wv>>1, wc=wv&1;
  f32x4 acc[4][4]={};
  const int c1=wv*64+ln, c2=c1+256;
  const int ar1=c1>>2, ak1=(c1&3)*8, ar2=c2>>2, ak2=(c2&3)*8;
  u16* aL1=&As[(size_t)(wv*64)*8]; u16* aL2=&As[(size_t)(256+wv*64)*8];
  u16* bL1=&Bs[(size_t)(wv*64)*8]; u16* bL2=&Bs[(size_t)(256+wv*64)*8];
  const u16* Ab=A+(size_t)m0*K;
  const u16* Bb=Bt+(size_t)n0*K;
  for(int kt=0;kt<K;kt+=32){
    gload16(Ab+(size_t)ar1*K+kt+ak1, aL1);
    gload16(Ab+(size_t)ar2*K+kt+ak2, aL2);
    gload16(Bb+(size_t)ar1*K+kt+ak1, bL1);
    gload16(Bb+(size_t)ar2*K+kt+ak2, bL2);
    __syncthreads();
    short8 af[4], bfr[4];
    #pragma unroll
    for(int i=0;i<4;i++) af[i]=*(const short8*)&As[(wr*64+i*16+(ln&15))*32+(ln>>4)*8];
    #pragma unroll
    for(int j=0;j<4;j++) bfr[j]=*(const short8*)&Bs[(wc*64+j*16+(ln&15))*32+(ln>>4)*8];
    #pragma unroll
    for(int i=0;i<4;i++)
      #pragma unroll
      for(int j=0;j<4;j++)
        acc[i][j]=__builtin_amdgcn_mfma_f32_16x16x32_bf16(af[i],bfr[j],acc[i][j],0,0,0);
    __syncthreads();
  }
  const int lr=ln>>4, lc=ln&15;
  #pragma unroll
  for(int i=0;i<4;i++){
    #pragma unroll
    for(int j=0;j<4;j++){
      const int row=m0+wr*64+i*16+lr*4;  // +r
      const int col=n0+wc*64+j*16+lc;
      const float bv=bias[col];
      if constexpr(EPI==0){
        u16* o=(u16*)outp;
        #pragma unroll
        for(int r=0;r<4;r++) o[(size_t)(row+r)*Ncol+col]=f2bf(acc[i][j][r]+bv);
      } else if constexpr(EPI==1){
        float* o=(float*)outp;
        #pragma unroll
        for(int r=0;r<4;r++){ size_t ix=(size_t)(row+r)*Ncol+col; o[ix]+=acc[i][j][r]+bv; }
      } else if constexpr(EPI==2){
        u16* o=(u16*)outp;
        #pragma unroll
        for(int r=0;r<4;r++){
          float v=acc[i][j][r]+bv;
          v=0.5f*v*(1.0f+erff(v*0.70710678118654752f)); // exact GELU
          o[(size_t)(row+r)*Ncol+col]=f2bf(v);
        }
      } else { // EPI==3: write vT[b,h,d,n] (rows of acc = 4 consecutive n)
        u16* vt=(u16*)outp;
        const int b_=row>>13, nn=row&(SEQ-1), h_=col>>6, d_=col&63;
        u16 pk[4];
        #pragma unroll
        for(int r=0;r<4;r++) pk[r]=f2bf(acc[i][j][r]+bv);
        uint2 pkv; pkv.x=(unsigned)pk[0]|((unsigned)pk[1]<<16); pkv.y=(unsigned)pk[2]|((unsigned)pk[3]<<16);
        *(uint2*)&vt[((size_t)(b_*HEADS+h_)*VROWS + d_)*SEQ + nn] = pkv;
      }
    }
  }
}

// ---------------- key pass 1: global max of dd per (b,h), plus diag(k) cache ----------------
__global__ __launch_bounds__(256) void k_pass1(const u16* __restrict__ kb, const u16* __restrict__ pj,
                                               unsigned* __restrict__ kmaxu, float* __restrict__ dgb){
  __shared__ u16 kl[128*64];
  const int bh=blockIdx.y, b_=bh>>3, h_=bh&7;
  const int n0=blockIdx.x*128;
  const int tid=threadIdx.x, wv=tid>>6, ln=tid&63;
  const u16* kg=kb+((size_t)(b_*SEQ+n0))*DIMX + h_*DHEAD;
  #pragma unroll
  for(int cc=0;cc<4;cc++){
    int c=cc*256+wv*64+ln;
    gload16(kg+(size_t)(c>>3)*DIMX+(c&7)*8, &kl[(size_t)(cc*256+wv*64)*8]);
  }
  __syncthreads();
  if(tid<128){
    float s=0;
    #pragma unroll
    for(int d=0;d<64;d++){ float v=bf2f(kl[tid*64+d]); s+=v*v; }
    dgb[(size_t)bh*SEQ + n0 + tid]=s*0.0625f;  // 0.5 * d^-0.5
  }
  f32x4 acc[4][8]={};
  #pragma unroll
  for(int dk=0;dk<64;dk+=32){
    short8 af[4];
    #pragma unroll
    for(int i=0;i<4;i++)
      af[i]=*(const short8*)&pj[(size_t)(wv*64+i*16+(ln&15))*DHEAD + dk + (ln>>4)*8];
    #pragma unroll
    for(int j=0;j<8;j++){
      short8 bf8=*(const short8*)&kl[(j*16+(ln&15))*64 + dk + (ln>>4)*8];
      #pragma unroll
      for(int i=0;i<4;i++)
        acc[i][j]=__builtin_amdgcn_mfma_f32_16x16x32_bf16(af[i],bf8,acc[i][j],0,0,0);
    }
  }
  float mx=-3.0e38f;
  #pragma unroll
  for(int i=0;i<4;i++)
    #pragma unroll
    for(int j=0;j<8;j++)
      #pragma unroll
      for(int r=0;r<4;r++) mx=fmaxf(mx,acc[i][j][r]);
  #pragma unroll
  for(int m=1;m<64;m<<=1) mx=fmaxf(mx,__shfl_xor(mx,m));
  if(ln==0) atomicMax(&kmaxu[bh], fenc(mx));
}

// ---------------- fused k-features + ctx partial GEMM ----------------
// per (chunk kc, bh): ctx_part[m=256][d=80] = sum over 512 tokens of kp[m,n]*vT[d,n]
__global__ __launch_bounds__(256) void kctx(const u16* __restrict__ kb, const u16* __restrict__ pj,
                                            const u16* __restrict__ vt, const unsigned* __restrict__ kmaxu,
                                            const float* __restrict__ dgb, float* __restrict__ part){
  __shared__ u16 kl[64*64];
  __shared__ u16 vl[80*64];
  __shared__ u16 kp_l[256*64];
  __shared__ float dgl[64];
  const int kc=blockIdx.x, bh=blockIdx.y, b_=bh>>3, h_=bh&7;
  const int tid=threadIdx.x, wv=tid>>6, ln=tid&63;
  const float km=fdec(kmaxu[bh]);
  short8 pjf[4][2];   // hoisted proj fragments: wave wv owns feature rows wv*64..+63
  #pragma unroll
  for(int i=0;i<4;i++)
    #pragma unroll
    for(int t=0;t<2;t++)
      pjf[i][t]=*(const short8*)&pj[(size_t)(wv*64+i*16+(ln&15))*DHEAD + t*32 + (ln>>4)*8];
  f32x4 ctx[4][5]={};
  const u16* vbh = vt + (size_t)bh*VROWS*SEQ;
  for(int s=0;s<8;s++){
    const int n0s = kc*512 + s*64;
    const u16* kg = kb + ((size_t)(b_*SEQ+n0s))*DIMX + h_*DHEAD;
    {
      int c0=wv*64+ln, c1=c0+256;
      gload16(kg+(size_t)(c0>>3)*DIMX+(c0&7)*8, &kl[(size_t)(wv*64)*8]);
      gload16(kg+(size_t)(c1>>3)*DIMX+(c1&7)*8, &kl[(size_t)(256+wv*64)*8]);
      gload16(vbh+(size_t)(c0>>3)*SEQ + n0s + (c0&7)*8, &vl[(size_t)(wv*64)*8]);
      gload16(vbh+(size_t)(c1>>3)*SEQ + n0s + (c1&7)*8, &vl[(size_t)(256+wv*64)*8]);
      if(wv<2){
        int c2=512+wv*64+ln;
        gload16(vbh+(size_t)(c2>>3)*SEQ + n0s + (c2&7)*8, &vl[(size_t)(512+wv*64)*8]);
      }
    }
    if(tid<64) dgl[tid]=dgb[(size_t)bh*SEQ + n0s + tid];
    __syncthreads();
    f32x4 dd[4][4]={};
    #pragma unroll
    for(int t=0;t<2;t++)
      #pragma unroll
      for(int j=0;j<4;j++){
        short8 bf8=*(const short8*)&kl[(j*16+(ln&15))*64 + t*32+(ln>>4)*8];
        #pragma unroll
        for(int i=0;i<4;i++)
          dd[i][j]=__builtin_amdgcn_mfma_f32_16x16x32_bf16(pjf[i][t],bf8,dd[i][j],0,0,0);
      }
    #pragma unroll
    for(int i=0;i<4;i++)
      #pragma unroll
      for(int j=0;j<4;j++)
        #pragma unroll
        for(int r=0;r<4;r++){
          int ml=wv*64+i*16+(ln>>4)*4+r;
          int nl=j*16+(ln&15);
          float v=0.0625f*(__expf(dd[i][j][r]-dgl[nl]-km)+1e-4f);
          kp_l[ml*64+nl]=f2bf(v);
        }
    // ctx += kp @ v^T  (kp_l rows are per-wave private: no barrier needed)
    #pragma unroll
    for(int t=0;t<2;t++){
      short8 af2[4];
      #pragma unroll
      for(int i=0;i<4;i++)
        af2[i]=*(const short8*)&kp_l[(wv*64+i*16+(ln&15))*64 + t*32+(ln>>4)*8];
      #pragma unroll
      for(int j=0;j<5;j++){
        short8 bf2=*(const short8*)&vl[(j*16+(ln&15))*64 + t*32+(ln>>4)*8];
        #pragma unroll
        for(int i=0;i<4;i++)
          ctx[i][j]=__builtin_amdgcn_mfma_f32_16x16x32_bf16(af2[i],bf2,ctx[i][j],0,0,0);
      }
    }
    __syncthreads();
  }
  float* po = part + ((size_t)(bh*NCHUNK+kc))*(256*80);
  #pragma unroll
  for(int i=0;i<4;i++)
    #pragma unroll
    for(int j=0;j<5;j++)
      #pragma unroll
      for(int r=0;r<4;r++)
        po[(size_t)(wv*64+i*16+(ln>>4)*4+r)*80 + j*16+(ln&15)]=ctx[i][j][r];
}

__global__ void ctx_reduce(const float* __restrict__ part, u16* __restrict__ ctxT, float* __restrict__ ksum){
  int idx=blockIdx.x*blockDim.x+threadIdx.x; // exactly 32*256*80
  int bh=idx/(NBFX*VROWS);
  int f=idx-bh*(NBFX*VROWS);
  int m=f/VROWS, d=f-m*VROWS;
  if(d>64) return;
  float s=0;
  #pragma unroll
  for(int c=0;c<NCHUNK;c++) s+=part[((size_t)(bh*NCHUNK+c))*(256*80) + (size_t)m*80 + d];
  if(d==64) ksum[bh*NBFX+m]=s;
  else      ctxT[((size_t)bh*64+d)*NBFX + m]=f2bf(s);
}

// ---------------- fused query path: features + softmax-kernel + O = (qp@ctx)*dinv ----------------
__global__ __launch_bounds__(256) void q_fused(const u16* __restrict__ qb, const u16* __restrict__ pj,
                                               const u16* __restrict__ ctxT, const float* __restrict__ ksum,
                                               u16* __restrict__ ob){
  __shared__ u16 ql[64*64];
  __shared__ u16 qpl[64*264];
  __shared__ float dg[64];
  const int bh=blockIdx.y, b_=bh>>3, h_=bh&7;
  const int n0=blockIdx.x*64;
  const int tid=threadIdx.x, wv=tid>>6, ln=tid&63;
  const u16* qg=qb+((size_t)(b_*SEQ+n0))*DIMX + h_*DHEAD;
  #pragma unroll
  for(int cc=0;cc<2;cc++){
    int c=cc*256+wv*64+ln;
    gload16(qg+(size_t)(c>>3)*DIMX+(c&7)*8, &ql[(size_t)(cc*256+wv*64)*8]);
  }
  __syncthreads();
  if(tid<64){
    float s=0;
    #pragma unroll
    for(int d=0;d<64;d++){ float v=bf2f(ql[tid*64+d]); s+=v*v; }
    dg[tid]=s*0.0625f;
  }
  __syncthreads();
  f32x4 dd[16]={};
  #pragma unroll
  for(int dk=0;dk<64;dk+=32){
    short8 aq=*(const short8*)&ql[(wv*16+(ln&15))*64+dk+(ln>>4)*8];
    #pragma unroll
    for(int j=0;j<16;j++){
      short8 bp=*(const short8*)&pj[(size_t)(j*16+(ln&15))*DHEAD+dk+(ln>>4)*8];
      dd[j]=__builtin_amdgcn_mfma_f32_16x16x32_bf16(aq,bp,dd[j],0,0,0);
    }
  }
  float ks[16];
  #pragma unroll
  for(int j=0;j<16;j++) ks[j]=ksum[bh*NBFX + j*16+(ln&15)];
  float dinv[4];
  #pragma unroll
  for(int r=0;r<4;r++){
    float mx=dd[0][r];
    #pragma unroll
    for(int j=1;j<16;j++) mx=fmaxf(mx,dd[j][r]);
    #pragma unroll
    for(int m=1;m<16;m<<=1) mx=fmaxf(mx,__shfl_xor(mx,m));
    const int rowl=wv*16+(ln>>4)*4+r;
    const float dgr=dg[rowl];
    float den=0.0f;
    #pragma unroll
    for(int j=0;j<16;j++){
      float v=0.0625f*(__expf(dd[j][r]-dgr-mx)+1e-4f);
      den+=v*ks[j];
      qpl[rowl*264 + j*16+(ln&15)]=f2bf(v);
    }
    #pragma unroll
    for(int m=1;m<16;m<<=1) den+=__shfl_xor(den,m);
    dinv[r]=1.0f/den;
  }
  __syncthreads();
  f32x4 oc[4]={};
  const u16* cb=ctxT+(size_t)bh*64*NBFX;
  #pragma unroll
  for(int mk=0;mk<256;mk+=32){
    short8 aq2=*(const short8*)&qpl[(wv*16+(ln&15))*264+mk+(ln>>4)*8];
    #pragma unroll
    for(int j=0;j<4;j++){
      short8 bc=*(const short8*)&cb[(size_t)(j*16+(ln&15))*NBFX+mk+(ln>>4)*8];
      oc[j]=__builtin_amdgcn_mfma_f32_16x16x32_bf16(aq2,bc,oc[j],0,0,0);
    }
  }
  u16* og=ob+((size_t)(b_*SEQ+n0))*DIMX + h_*DHEAD;
  #pragma unroll
  for(int j=0;j<4;j++)
    #pragma unroll
    for(int r=0;r<4;r++)
      og[(size_t)(wv*16+(ln>>4)*4+r)*DIMX + j*16+(ln&15)]=f2bf(oc[j][r]*dinv[r]);
}

// ---------------- workspace layout (total ~190.1 MiB) ----------------
static constexpr size_t SZ_ACT=(size_t)TOK*DIMX*2;                 // 32 MiB
static constexpr size_t O_Y=0, O_Q=SZ_ACT, O_K=2*SZ_ACT;
static constexpr size_t O_VT=3*SZ_ACT;                             // 96 MiB
static constexpr size_t SZ_VT=(size_t)NBH*VROWS*SEQ*2;             // 40 MiB
static constexpr size_t O_PART=O_VT+SZ_VT;
static constexpr size_t SZ_PART=(size_t)NBH*NCHUNK*256*80*4;       // 40 MiB
static constexpr size_t O_CTXT=O_PART+SZ_PART;
static constexpr size_t SZ_CTXT=(size_t)NBH*64*NBFX*2;             // 1 MiB
static constexpr size_t O_KSUM=O_CTXT+SZ_CTXT;
static constexpr size_t SZ_KSUM=(size_t)NBH*NBFX*4;
static constexpr size_t O_KMAX=O_KSUM+SZ_KSUM;
static constexpr size_t O_DG=O_KMAX+256;
static constexpr size_t SZ_DG=(size_t)NBH*SEQ*4;                   // 1 MiB
static constexpr size_t O_WQT=O_DG+SZ_DG;
static constexpr size_t SZ_W=(size_t)2*DIMX*DIMX*2;                // 1 MiB
static constexpr size_t O_WKT=O_WQT+SZ_W, O_WVT=O_WKT+SZ_W, O_WOT=O_WVT+SZ_W;
static constexpr size_t O_W1T=O_WOT+SZ_W;
static constexpr size_t SZ_W1=(size_t)2*FFD*DIMX*2;                // 4 MiB
static constexpr size_t O_W2T=O_W1T+SZ_W1;
static constexpr size_t O_PJ=O_W2T+SZ_W1;
static constexpr size_t WS_END=O_PJ+(size_t)2*NBFX*DHEAD*2;

extern "C" void kernel_launch(void* const* d_in, const int* in_sizes, int n_in,
                              void* d_out, int out_size, void* d_ws, size_t ws_size,
                              hipStream_t stream){
  (void)in_sizes;(void)n_in;(void)out_size;
  const float* xin =(const float*)d_in[0];
  const float* ln1g=(const float*)d_in[1];
  const float* ln1b=(const float*)d_in[2];
  const float* ln2g=(const float*)d_in[3];
  const float* ln2b=(const float*)d_in[4];
  const float* Wq=(const float*)d_in[5];
  const float* bq=(const float*)d_in[6];
  const float* Wk=(const float*)d_in[7];
  const float* bk=(const float*)d_in[8];
  const float* Wv=(const float*)d_in[9];
  const float* bv=(const float*)d_in[10];
  const float* Wo=(const float*)d_in[11];
  const float* bo=(const float*)d_in[12];
  const float* proj=(const float*)d_in[13];
  const float* W1=(const float*)d_in[14];
  const float* b1=(const float*)d_in[15];
  const float* W2=(const float*)d_in[16];
  const float* b2=(const float*)d_in[17];
  float* xout=(float*)d_out;

  // diagnostic fallback: if ws too small, emit input copy (absmax-fail, not crash)
  copy_f32<<<(TOK*DIMX/4)/256,256,0,stream>>>((const float4*)xin,(float4*)xout, TOK*DIMX/4);
  if(ws_size < WS_END) return;

  char* ws=(char*)d_ws;
  u16* ybuf =(u16*)(ws+O_Y);
  u16* qbuf =(u16*)(ws+O_Q);
  u16* kbuf =(u16*)(ws+O_K);
  u16* vtb  =(u16*)(ws+O_VT);
  float* partb=(float*)(ws+O_PART);
  u16* ctxtb=(u16*)(ws+O_CTXT);
  float* ksumb=(float*)(ws+O_KSUM);
  unsigned* kmaxu=(unsigned*)(ws+O_KMAX);
  float* dgb=(float*)(ws+O_DG);
  u16* wqt=(u16*)(ws+O_WQT); u16* wkt=(u16*)(ws+O_WKT);
  u16* wvt=(u16*)(ws+O_WVT); u16* wot=(u16*)(ws+O_WOT);
  u16* w1t=(u16*)(ws+O_W1T); u16* w2t=(u16*)(ws+O_W2T);
  u16* pjb=(u16*)(ws+O_PJ);
  u16* hbuf=(u16*)(ws+O_Q);   // FF hidden chunk (64 MiB) reuses dead q+k regions

  for(int l=0;l<2;l++){
    size_t wo=(size_t)l*DIMX*DIMX;
    convT<<<dim3(16,16),dim3(32,8),0,stream>>>(Wq+wo, wqt+wo, DIMX, DIMX);
    convT<<<dim3(16,16),dim3(32,8),0,stream>>>(Wk+wo, wkt+wo, DIMX, DIMX);
    convT<<<dim3(16,16),dim3(32,8),0,stream>>>(Wv+wo, wvt+wo, DIMX, DIMX);
    convT<<<dim3(16,16),dim3(32,8),0,stream>>>(Wo+wo, wot+wo, DIMX, DIMX);
    size_t w1o=(size_t)l*DIMX*FFD;
    convT<<<dim3(64,16),dim3(32,8),0,stream>>>(W1+w1o, w1t+w1o, DIMX, FFD);
    convT<<<dim3(16,64),dim3(32,8),0,stream>>>(W2+w1o, w2t+w1o, FFD, DIMX);
  }
  conv_proj<<<(2*NBFX*DHEAD)/256,256,0,stream>>>(proj, pjb, 2*NBFX*DHEAD);
  fill_vt<<<(NBH*16*SEQ)/256,256,0,stream>>>(vtb);

  for(int l=0;l<2;l++){
    const u16* wqt_l=wqt+(size_t)l*DIMX*DIMX;
    const u16* wkt_l=wkt+(size_t)l*DIMX*DIMX;
    const u16* wvt_l=wvt+(size_t)l*DIMX*DIMX;
    const u16* wot_l=wot+(size_t)l*DIMX*DIMX;
    const u16* w1t_l=w1t+(size_t)l*DIMX*FFD;
    const u16* w2t_l=w2t+(size_t)l*DIMX*FFD;
    const u16* pj_l =pjb+(size_t)l*NBFX*DHEAD;

    ln_k<<<TOK,256,0,stream>>>(xout, ln1g+l*DIMX, ln1b+l*DIMX, ybuf);
    gemm_bt<0><<<dim3(4,256),256,0,stream>>>(ybuf, wqt_l, bq+l*DIMX, qbuf, TOK, DIMX, DIMX);
    gemm_bt<0><<<dim3(4,256),256,0,stream>>>(ybuf, wkt_l, bk+l*DIMX, kbuf, TOK, DIMX, DIMX);
    gemm_bt<3><<<dim3(4,256),256,0,stream>>>(ybuf, wvt_l, bv+l*DIMX, vtb, TOK, DIMX, DIMX);
    kinit<<<1,64,0,stream>>>(kmaxu);
    k_pass1<<<dim3(64,32),256,0,stream>>>(kbuf, pj_l, kmaxu, dgb);
    kctx<<<dim3(NCHUNK,32),256,0,stream>>>(kbuf, pj_l, vtb, kmaxu, dgb, partb);
    ctx_reduce<<<(NBH*NBFX*VROWS)/256,256,0,stream>>>(partb, ctxtb, ksumb);
    q_fused<<<dim3(128,32),256,0,stream>>>(qbuf, pj_l, ctxtb, ksumb, ybuf);
    gemm_bt<1><<<dim3(4,256),256,0,stream>>>(ybuf, wot_l, bo+l*DIMX, xout, TOK, DIMX, DIMX);
    ln_k<<<TOK,256,0,stream>>>(xout, ln2g+l*DIMX, ln2b+l*DIMX, ybuf);
    for(int c=0;c<2;c++){
      gemm_bt<2><<<dim3(16,128),256,0,stream>>>(ybuf+(size_t)c*16384*DIMX, w1t_l, b1+l*FFD, hbuf, 16384, FFD, DIMX);
      gemm_bt<1><<<dim3(4,128),256,0,stream>>>(hbuf, w2t_l, b2+l*DIMX, xout+(size_t)c*16384*DIMX, 16384, DIMX, FFD);
    }
  }
}

// Round 3
// 1324.340 us; speedup vs baseline: 1.2562x; 1.2562x over previous
//
#include <hip/hip_runtime.h>
#include <math.h>

#define DIMX 512
#define HEADS 8
#define DHEAD 64
#define NBFX 256
#define FFD 2048
#define NBX 4
#define SEQ 8192
#define TOK (NBX*SEQ)     // 32768 tokens
#define NBH (NBX*HEADS)   // 32 (b,h) pairs
#define VROWS 80          // 64 v-dims + ones row(64) + zeros pad
#define NCHUNK 16         // ctx K-split chunks (512 tokens each)

typedef unsigned short u16;
typedef __attribute__((ext_vector_type(8))) short short8;
typedef __attribute__((ext_vector_type(4))) float f32x4;

__device__ __forceinline__ float bf2f(u16 x){ return __uint_as_float(((unsigned)x)<<16); }
__device__ __forceinline__ u16 f2bf(float f){
  unsigned u=__float_as_uint(f);
  return (u16)((u + 0x7FFFu + ((u>>16)&1u))>>16);
}
__device__ __forceinline__ void gload16(const void* g, void* l){
  __builtin_amdgcn_global_load_lds((const __attribute__((address_space(1))) void*)g,
                                   (__attribute__((address_space(3))) void*)l, 16, 0, 0);
}

// ---------------- prep / elementwise ----------------
__global__ void copy_f32(const float4* __restrict__ s, float4* __restrict__ d, int n4){
  int i=blockIdx.x*blockDim.x+threadIdx.x;
  if(i<n4) d[i]=s[i];
}
__global__ void conv_proj(const float* __restrict__ p, u16* __restrict__ o, int n){
  int i=blockIdx.x*blockDim.x+threadIdx.x;
  if(i<n) o[i]=f2bf(p[i]*0.35355339059327373f); // fold d^-0.25 into proj
}
// src fp32 [K][Ncol] -> dst bf16 [Ncol][K] (transposed)
__global__ void convT(const float* __restrict__ src, u16* __restrict__ dst, int K, int Ncol){
  __shared__ float t[32][33];
  int k0=blockIdx.y*32, n0=blockIdx.x*32;
  int tx=threadIdx.x, ty=threadIdx.y;
  for(int i=ty;i<32;i+=8) t[i][tx]=src[(size_t)(k0+i)*Ncol + n0+tx];
  __syncthreads();
  for(int i=ty;i<32;i+=8) dst[(size_t)(n0+i)*K + k0+tx]=f2bf(t[tx][i]);
}
// vT rows 64..79: row 64 = ones (k_sum trick), 65..79 = zeros
__global__ void fill_vt(u16* __restrict__ vt){
  int i=blockIdx.x*blockDim.x+threadIdx.x; // < NBH*16*SEQ = 2^22
  int n=i&(SEQ-1); int r=(i>>13)&15; int bh=i>>17;
  vt[((size_t)bh*VROWS + 64 + r)*SEQ + n] = (r==0)? (u16)0x3F80 : (u16)0;
}

__global__ __launch_bounds__(256) void ln_k(const float* __restrict__ x, const float* __restrict__ g,
                                            const float* __restrict__ b, u16* __restrict__ y){
  int row=blockIdx.x, t=threadIdx.x;
  const float* xr=x+(size_t)row*DIMX;
  float2 v=*(const float2*)&xr[t*2];
  float s=v.x+v.y;
  #pragma unroll
  for(int m=1;m<64;m<<=1) s+=__shfl_xor(s,m);
  __shared__ float red[8];
  if((t&63)==0) red[t>>6]=s;
  __syncthreads();
  float mean=(red[0]+red[1]+red[2]+red[3])*(1.0f/DIMX);
  float dx=v.x-mean, dy=v.y-mean;
  float s2=dx*dx+dy*dy;
  #pragma unroll
  for(int m=1;m<64;m<<=1) s2+=__shfl_xor(s2,m);
  if((t&63)==0) red[4+(t>>6)]=s2;
  __syncthreads();
  float var=(red[4]+red[5]+red[6]+red[7])*(1.0f/DIMX);
  float rs=rsqrtf(var+1e-5f);
  u16* yr=y+(size_t)row*DIMX;
  yr[t*2  ]=f2bf(dx*rs*g[t*2  ]+b[t*2  ]);
  yr[t*2+1]=f2bf(dy*rs*g[t*2+1]+b[t*2+1]);
}

// ---------------- generic bf16 MFMA GEMM: C = A[M,K] * Bt[N,K]^T + bias ----------------
// EPI 0: bf16 out; 1: fp32 out += (residual in-place); 2: gelu->bf16; 3: V-transposed bf16 out
template<int EPI>
__global__ __launch_bounds__(256) void gemm_bt(const u16* __restrict__ A, const u16* __restrict__ Bt,
                                               const float* __restrict__ bias, void* __restrict__ outp,
                                               int M, int Ncol, int K){
  __shared__ u16 As[128*32];
  __shared__ u16 Bs[128*32];
  const int m0=blockIdx.y*128, n0=blockIdx.x*128;
  const int tid=threadIdx.x, wv=tid>>6, ln=tid&63;
  const int wr=wv>>1, wc=wv&1;
  f32x4 acc[4][4]={};
  const int c1=wv*64+ln, c2=c1+256;
  const int ar1=c1>>2, ak1=(c1&3)*8, ar2=c2>>2, ak2=(c2&3)*8;
  u16* aL1=&As[(size_t)(wv*64)*8]; u16* aL2=&As[(size_t)(256+wv*64)*8];
  u16* bL1=&Bs[(size_t)(wv*64)*8]; u16* bL2=&Bs[(size_t)(256+wv*64)*8];
  const u16* Ab=A+(size_t)m0*K;
  const u16* Bb=Bt+(size_t)n0*K;
  for(int kt=0;kt<K;kt+=32){
    gload16(Ab+(size_t)ar1*K+kt+ak1, aL1);
    gload16(Ab+(size_t)ar2*K+kt+ak2, aL2);
    gload16(Bb+(size_t)ar1*K+kt+ak1, bL1);
    gload16(Bb+(size_t)ar2*K+kt+ak2, bL2);
    __syncthreads();
    short8 af[4], bfr[4];
    #pragma unroll
    for(int i=0;i<4;i++) af[i]=*(const short8*)&As[(wr*64+i*16+(ln&15))*32+(ln>>4)*8];
    #pragma unroll
    for(int j=0;j<4;j++) bfr[j]=*(const short8*)&Bs[(wc*64+j*16+(ln&15))*32+(ln>>4)*8];
    #pragma unroll
    for(int i=0;i<4;i++)
      #pragma unroll
      for(int j=0;j<4;j++)
        acc[i][j]=__builtin_amdgcn_mfma_f32_16x16x32_bf16(af[i],bfr[j],acc[i][j],0,0,0);
    __syncthreads();
  }
  const int lr=ln>>4, lc=ln&15;
  #pragma unroll
  for(int i=0;i<4;i++){
    #pragma unroll
    for(int j=0;j<4;j++){
      const int row=m0+wr*64+i*16+lr*4;  // +r
      const int col=n0+wc*64+j*16+lc;
      const float bv=bias[col];
      if constexpr(EPI==0){
        u16* o=(u16*)outp;
        #pragma unroll
        for(int r=0;r<4;r++) o[(size_t)(row+r)*Ncol+col]=f2bf(acc[i][j][r]+bv);
      } else if constexpr(EPI==1){
        float* o=(float*)outp;
        #pragma unroll
        for(int r=0;r<4;r++){ size_t ix=(size_t)(row+r)*Ncol+col; o[ix]+=acc[i][j][r]+bv; }
      } else if constexpr(EPI==2){
        u16* o=(u16*)outp;
        #pragma unroll
        for(int r=0;r<4;r++){
          float v=acc[i][j][r]+bv;
          v=0.5f*v*(1.0f+erff(v*0.70710678118654752f)); // exact GELU
          o[(size_t)(row+r)*Ncol+col]=f2bf(v);
        }
      } else { // EPI==3: write vT[b,h,d,n] (rows of acc = 4 consecutive n)
        u16* vt=(u16*)outp;
        const int b_=row>>13, nn=row&(SEQ-1), h_=col>>6, d_=col&63;
        u16 pk[4];
        #pragma unroll
        for(int r=0;r<4;r++) pk[r]=f2bf(acc[i][j][r]+bv);
        uint2 pkv; pkv.x=(unsigned)pk[0]|((unsigned)pk[1]<<16); pkv.y=(unsigned)pk[2]|((unsigned)pk[3]<<16);
        *(uint2*)&vt[((size_t)(b_*HEADS+h_)*VROWS + d_)*SEQ + nn] = pkv;
      }
    }
  }
}

// ---------------- vsum: per (bh,d<=64) row-sum of vT over all n ----------------
__global__ __launch_bounds__(256) void vsum_k(const u16* __restrict__ vt, float* __restrict__ vs){
  const int gw=blockIdx.x*4 + (threadIdx.x>>6); // 0..2079 = 32*65
  const int ln=threadIdx.x&63;
  const int bh=gw/65, d=gw-bh*65;
  const u16* row=vt+((size_t)bh*VROWS+d)*SEQ;
  float s=0;
  for(int it=0;it<16;it++){
    short8 v=*(const short8*)&row[it*512+ln*8];
    #pragma unroll
    for(int e=0;e<8;e++) s+=bf2f((u16)v[e]);
  }
  #pragma unroll
  for(int m=1;m<64;m<<=1) s+=__shfl_xor(s,m);
  if(ln==0) vs[bh*80+d]=s;
}

// ---------------- fused k-features + ctx partial GEMM (deferred max) ----------------
// grid (NCHUNK, 2 halves, 32 bh). Wave owns m rows half*128+wv*32+[0,32).
// part[(bh*NCHUNK+kc)*256*80 + m*80 + d] = sum_{n in chunk} exp(dd - diag - m_cw)*vT[d][n]
// maxb[bh*128 + kc*8 + half*4 + wv] = m_cw (per-wave running max of dd over chunk)
__global__ __launch_bounds__(256) void kctx(const u16* __restrict__ kb, const u16* __restrict__ pj,
                                            const u16* __restrict__ vt,
                                            float* __restrict__ part, float* __restrict__ maxb){
  __shared__ u16 kl[64*64];     // [token][d], granule-swizzled by token&7
  __shared__ u16 vl[80*64];     // [d][n],     granule-swizzled by d&7
  __shared__ u16 kp_l[128*64];  // [m_local][n], granule-swizzled by m&7 (per-wave rows)
  __shared__ float dgl[64];
  const int kc=blockIdx.x, half=blockIdx.y, bh=blockIdx.z, b_=bh>>3, h_=bh&7;
  const int tid=threadIdx.x, wv=tid>>6, ln=tid&63;
  // hoist proj fragments: rows m = half*128 + wv*32 + i*16 + (ln&15)
  short8 pjf[2][2];
  #pragma unroll
  for(int i=0;i<2;i++)
    #pragma unroll
    for(int t=0;t<2;t++)
      pjf[i][t]=*(const short8*)&pj[(size_t)(half*128+wv*32+i*16+(ln&15))*DHEAD + t*32 + (ln>>4)*8];
  f32x4 ctx[2][5]={};
  float m_run=-3.0e38f;
  const u16* vbh=vt+(size_t)bh*VROWS*SEQ;
  for(int s=0;s<8;s++){
    const int n0s=kc*512+s*64;
    const u16* kg=kb+((size_t)(b_*SEQ+n0s))*DIMX + h_*DHEAD;
    #pragma unroll
    for(int cc=0;cc<2;cc++){
      int c=cc*256+wv*64+ln; int t=c>>3, g=c&7;
      gload16(kg+(size_t)t*DIMX+((g^(t&7))*8), &kl[(size_t)(cc*256+wv*64)*8]);
    }
    #pragma unroll
    for(int cc=0;cc<2;cc++){
      int c=cc*256+wv*64+ln; int d=c>>3, g=c&7;
      gload16(vbh+(size_t)d*SEQ+n0s+((g^(d&7))*8), &vl[(size_t)(cc*256+wv*64)*8]);
    }
    if(wv<2){
      int c=512+wv*64+ln; int d=c>>3, g=c&7;
      gload16(vbh+(size_t)d*SEQ+n0s+((g^(d&7))*8), &vl[(size_t)(512+wv*64)*8]);
    }
    __syncthreads();
    if(tid<64){ // diag(k): rotated+any-order granule reads (sum over all 8)
      float ss=0;
      #pragma unroll
      for(int gg=0;gg<8;gg++){
        short8 kv=*(const short8*)&kl[tid*64 + ((gg+tid)&7)*8];
        #pragma unroll
        for(int e=0;e<8;e++){ float x=bf2f((u16)kv[e]); ss+=x*x; }
      }
      dgl[tid]=ss*0.0625f; // 0.5 * d^-0.5
    }
    __syncthreads();
    // dd[i][j]: rows m (wave's 32), cols n (64 tokens)
    f32x4 dd[2][4]={};
    #pragma unroll
    for(int tk=0;tk<2;tk++)
      #pragma unroll
      for(int j=0;j<4;j++){
        short8 bk_=*(const short8*)&kl[(j*16+(ln&15))*64 + (((tk*4+(ln>>4))^(ln&7))<<3)];
        #pragma unroll
        for(int i=0;i<2;i++)
          dd[i][j]=__builtin_amdgcn_mfma_f32_16x16x32_bf16(pjf[i][tk],bk_,dd[i][j],0,0,0);
      }
    // wave-wide max of this tile
    float mt=-3.0e38f;
    #pragma unroll
    for(int i=0;i<2;i++)
      #pragma unroll
      for(int j=0;j<4;j++)
        #pragma unroll
        for(int r=0;r<4;r++) mt=fmaxf(mt,dd[i][j][r]);
    #pragma unroll
    for(int m=1;m<64;m<<=1) mt=fmaxf(mt,__shfl_xor(mt,m));
    if(mt>m_run){
      float sc=__expf(m_run-mt); // first iter: exp(-huge)=0, ctx already 0
      #pragma unroll
      for(int i=0;i<2;i++)
        #pragma unroll
        for(int j2=0;j2<5;j2++) ctx[i][j2]*=sc;
      m_run=mt;
    }
    // exp + store kp (per-wave private rows)
    #pragma unroll
    for(int j=0;j<4;j++){
      const float dgn=dgl[j*16+(ln&15)];
      #pragma unroll
      for(int i=0;i<2;i++)
        #pragma unroll
        for(int r=0;r<4;r++){
          int m_l=wv*32+i*16+(ln>>4)*4+r;
          float E=__expf(dd[i][j][r]-dgn-m_run);
          kp_l[m_l*64 + (((j*2+((ln>>3)&1))^(m_l&7))<<3) + (ln&7)]=f2bf(E);
        }
    }
    // ctx += kp @ v^T (same-wave write->read, ordered by DS queue)
    #pragma unroll
    for(int tk=0;tk<2;tk++){
      short8 af2[2];
      #pragma unroll
      for(int i=0;i<2;i++)
        af2[i]=*(const short8*)&kp_l[(wv*32+i*16+(ln&15))*64 + (((tk*4+(ln>>4))^(ln&7))<<3)];
      #pragma unroll
      for(int j2=0;j2<5;j2++){
        short8 bf2=*(const short8*)&vl[(j2*16+(ln&15))*64 + (((tk*4+(ln>>4))^(ln&7))<<3)];
        #pragma unroll
        for(int i=0;i<2;i++)
          ctx[i][j2]=__builtin_amdgcn_mfma_f32_16x16x32_bf16(af2[i],bf2,ctx[i][j2],0,0,0);
      }
    }
    __syncthreads();
  }
  float* po=part + ((size_t)(bh*NCHUNK+kc))*(256*80) + (size_t)half*128*80;
  #pragma unroll
  for(int i=0;i<2;i++)
    #pragma unroll
    for(int j2=0;j2<5;j2++)
      #pragma unroll
      for(int r=0;r<4;r++)
        po[(size_t)(wv*32+i*16+(ln>>4)*4+r)*80 + j2*16+(ln&15)]=ctx[i][j2][r];
  if(ln==0) maxb[bh*128 + kc*8 + half*4 + wv]=m_run;
}

// ---------------- ctx reduce: rescale chunk partials + analytic eps ----------------
// grid (8 msegs, 32 bh); block handles 32 m-rows (one half+wave slice) x 80 d
__global__ __launch_bounds__(256) void ctx_reduce(const float* __restrict__ part, const float* __restrict__ maxb,
                                                  const float* __restrict__ vs,
                                                  u16* __restrict__ ctxT, float* __restrict__ ksum){
  __shared__ float mx_s[128];
  __shared__ float sc_s[NCHUNK];
  const int mseg=blockIdx.x, bh=blockIdx.y, tid=threadIdx.x;
  if(tid<128) mx_s[tid]=maxb[(size_t)bh*128+tid];
  __syncthreads();
  float km=-3.0e38f;
  for(int i=0;i<128;i++) km=fmaxf(km,mx_s[i]);
  const int m0=mseg*32;
  const int half=m0>>7, wvv=(m0&127)>>5;
  if(tid<NCHUNK) sc_s[tid]=__expf(mx_s[tid*8+half*4+wvv]-km);
  __syncthreads();
  for(int rep=0;rep<10;rep++){
    int idx=rep*256+tid;           // 0..2559 = 32*80
    int mo=idx/80, d=idx-mo*80;
    int m=m0+mo;
    float s=0;
    #pragma unroll
    for(int c=0;c<NCHUNK;c++)
      s+=sc_s[c]*part[((size_t)(bh*NCHUNK+c))*(256*80) + (size_t)m*80 + d];
    float vsd=(d<=64)? vs[bh*80+d] : 0.0f;
    float val=0.0625f*(s + 1e-4f*vsd);
    if(d<64)       ctxT[((size_t)bh*64+d)*NBFX + m]=f2bf(val);
    else if(d==64) ksum[bh*NBFX+m]=val;
  }
}

// ---------------- column sums of ctxT / ksum (for analytic eps on q side) ----------------
__global__ void csum_k(const u16* __restrict__ ctxT, const float* __restrict__ ksum, float* __restrict__ cs){
  const int bh=blockIdx.x, t=threadIdx.x;
  if(t<64){
    const u16* r=ctxT+((size_t)bh*64+t)*NBFX;
    float s=0;
    for(int m=0;m<NBFX;m+=8){
      short8 v=*(const short8*)&r[m];
      #pragma unroll
      for(int e=0;e<8;e++) s+=bf2f((u16)v[e]);
    }
    cs[bh*80+t]=s;
  } else if(t==64){
    float s=0;
    for(int m=0;m<NBFX;m++) s+=ksum[bh*NBFX+m];
    cs[bh*80+64]=s;
  }
}

// ---------------- fused query path (no-max E-form) ----------------
// E' = exp(dd - dg); o[n,d] = (sum_m E'*ctx[m,d] + eps*e^{mx_n}*CS_d) /
//                            (sum_m E'*ksum[m] + eps*e^{mx_n}*KS)
__global__ __launch_bounds__(256) void q_fused(const u16* __restrict__ qb, const u16* __restrict__ pj,
                                               const u16* __restrict__ ctxT, const float* __restrict__ ksum,
                                               const float* __restrict__ cs, u16* __restrict__ ob){
  __shared__ u16 ql[64*64];     // [token][d], granule-swizzled by token&7
  __shared__ u16 qpl[64*136];   // [token n][m_local 128 + pad]
  __shared__ float dgs[64];
  __shared__ float mred[4*64], dred[4*64];
  __shared__ float ff_s[64], dinv_s[64];
  const int bh=blockIdx.y, b_=bh>>3, h_=bh&7;
  const int n0=blockIdx.x*64;
  const int tid=threadIdx.x, wv=tid>>6, ln=tid&63;
  const u16* qg=qb+((size_t)(b_*SEQ+n0))*DIMX + h_*DHEAD;
  #pragma unroll
  for(int cc=0;cc<2;cc++){
    int c=cc*256+wv*64+ln; int t=c>>3, g=c&7;
    gload16(qg+(size_t)t*DIMX+((g^(t&7))*8), &ql[(size_t)(cc*256+wv*64)*8]);
  }
  // hoist proj fragments (both halves) and ksum values for wave's m rows
  short8 pjf[2][2][2];
  float ks[2][2][4];
  #pragma unroll
  for(int h=0;h<2;h++)
    #pragma unroll
    for(int i=0;i<2;i++){
      #pragma unroll
      for(int t=0;t<2;t++)
        pjf[h][i][t]=*(const short8*)&pj[(size_t)(h*128+wv*32+i*16+(ln&15))*DHEAD + t*32 + (ln>>4)*8];
      #pragma unroll
      for(int r=0;r<4;r++)
        ks[h][i][r]=ksum[bh*NBFX + h*128+wv*32+i*16+(ln>>4)*4+r];
    }
  const float KS=cs[bh*80+64];
  __syncthreads();
  if(tid<64){ // diag(q)
    float ss=0;
    #pragma unroll
    for(int gg=0;gg<8;gg++){
      short8 kv=*(const short8*)&ql[tid*64 + ((gg+tid)&7)*8];
      #pragma unroll
      for(int e=0;e<8;e++){ float x=bf2f((u16)kv[e]); ss+=x*x; }
    }
    dgs[tid]=ss*0.0625f;
  }
  __syncthreads();
  float mxp[4]={-3.0e38f,-3.0e38f,-3.0e38f,-3.0e38f};
  float dnp[4]={0,0,0,0};
  f32x4 oc[4]={};
  const u16* cb=ctxT+(size_t)bh*64*NBFX;
  #pragma unroll
  for(int h=0;h<2;h++){
    // feature phase: dd rows m (wave's 32 within half), cols n
    #pragma unroll
    for(int j=0;j<4;j++){
      f32x4 dq[2]={};
      #pragma unroll
      for(int tk=0;tk<2;tk++){
        short8 bq=*(const short8*)&ql[(j*16+(ln&15))*64 + (((tk*4+(ln>>4))^(ln&7))<<3)];
        #pragma unroll
        for(int i=0;i<2;i++)
          dq[i]=__builtin_amdgcn_mfma_f32_16x16x32_bf16(pjf[h][i][tk],bq,dq[i],0,0,0);
      }
      const float dgn=dgs[j*16+(ln&15)];
      #pragma unroll
      for(int i=0;i<2;i++)
        #pragma unroll
        for(int r=0;r<4;r++){
          float d_=dq[i][r];
          mxp[j]=fmaxf(mxp[j],d_);
          float E=__expf(d_-dgn);
          dnp[j]+=E*ks[h][i][r];
          qpl[(j*16+(ln&15))*136 + wv*32+i*16+(ln>>4)*4+r]=f2bf(E);
        }
    }
    __syncthreads();
    // O partial: O^T[d][n] += ctxT[d][m-half] * qp[n][m-half]
    #pragma unroll
    for(int mk2=0;mk2<4;mk2++){
      short8 aq=*(const short8*)&cb[(size_t)(wv*16+(ln&15))*NBFX + h*128 + mk2*32 + (ln>>4)*8];
      #pragma unroll
      for(int j2=0;j2<4;j2++){
        short8 bqp=*(const short8*)&qpl[(j2*16+(ln&15))*136 + mk2*32 + (ln>>4)*8];
        oc[j2]=__builtin_amdgcn_mfma_f32_16x16x32_bf16(aq,bqp,oc[j2],0,0,0);
      }
    }
    __syncthreads();
  }
  // reduce mx/den over lane-groups then waves
  #pragma unroll
  for(int j=0;j<4;j++){
    #pragma unroll
    for(int msk=16;msk<64;msk<<=1){
      mxp[j]=fmaxf(mxp[j],__shfl_xor(mxp[j],msk));
      dnp[j]+=__shfl_xor(dnp[j],msk);
    }
  }
  if(ln<16){
    #pragma unroll
    for(int j=0;j<4;j++){ mred[wv*64+j*16+ln]=mxp[j]; dred[wv*64+j*16+ln]=dnp[j]; }
  }
  __syncthreads();
  if(tid<64){
    float mx=fmaxf(fmaxf(mred[tid],mred[64+tid]),fmaxf(mred[128+tid],mred[192+tid]));
    float dn=dred[tid]+dred[64+tid]+dred[128+tid]+dred[192+tid];
    float f=1e-4f*__expf(mx);
    ff_s[tid]=f;
    dinv_s[tid]=1.0f/(dn + f*KS);
  }
  __syncthreads();
  // epilogue: lane holds O^T[d = wv*16+(ln>>4)*4+r][n = j2*16+(ln&15)]
  float csr[4];
  #pragma unroll
  for(int r=0;r<4;r++) csr[r]=cs[bh*80 + wv*16+(ln>>4)*4+r];
  u16* og=ob+((size_t)(b_*SEQ+n0))*DIMX + h_*DHEAD;
  #pragma unroll
  for(int j2=0;j2<4;j2++){
    int n=j2*16+(ln&15);
    float f=ff_s[n], di=dinv_s[n];
    u16 pk[4];
    #pragma unroll
    for(int r=0;r<4;r++) pk[r]=f2bf((oc[j2][r]+f*csr[r])*di);
    uint2 pv; pv.x=(unsigned)pk[0]|((unsigned)pk[1]<<16); pv.y=(unsigned)pk[2]|((unsigned)pk[3]<<16);
    *(uint2*)&og[(size_t)n*DIMX + wv*16+(ln>>4)*4]=pv;
  }
}

// ---------------- workspace layout (~189.1 MiB) ----------------
static constexpr size_t SZ_ACT=(size_t)TOK*DIMX*2;                 // 32 MiB
static constexpr size_t O_Y=0, O_Q=SZ_ACT, O_K=2*SZ_ACT;
static constexpr size_t O_VT=3*SZ_ACT;                             // 96 MiB
static constexpr size_t SZ_VT=(size_t)NBH*VROWS*SEQ*2;             // 40 MiB
static constexpr size_t O_PART=O_VT+SZ_VT;
static constexpr size_t SZ_PART=(size_t)NBH*NCHUNK*256*80*4;       // 40 MiB
static constexpr size_t O_CTXT=O_PART+SZ_PART;
static constexpr size_t SZ_CTXT=(size_t)NBH*64*NBFX*2;             // 1 MiB
static constexpr size_t O_KSUM=O_CTXT+SZ_CTXT;
static constexpr size_t SZ_KSUM=(size_t)NBH*NBFX*4;
static constexpr size_t O_MAX=O_KSUM+SZ_KSUM;
static constexpr size_t SZ_MAX=(size_t)NBH*128*4;
static constexpr size_t O_VSUM=O_MAX+SZ_MAX;
static constexpr size_t SZ_VSUM=(size_t)NBH*80*4;
static constexpr size_t O_CS=O_VSUM+SZ_VSUM;
static constexpr size_t SZ_CS=(size_t)NBH*80*4;
static constexpr size_t O_WQT=O_CS+SZ_CS;
static constexpr size_t SZ_W=(size_t)2*DIMX*DIMX*2;                // 1 MiB
static constexpr size_t O_WKT=O_WQT+SZ_W, O_WVT=O_WKT+SZ_W, O_WOT=O_WVT+SZ_W;
static constexpr size_t O_W1T=O_WOT+SZ_W;
static constexpr size_t SZ_W1=(size_t)2*FFD*DIMX*2;                // 4 MiB
static constexpr size_t O_W2T=O_W1T+SZ_W1;
static constexpr size_t O_PJ=O_W2T+SZ_W1;
static constexpr size_t WS_END=O_PJ+(size_t)2*NBFX*DHEAD*2;

extern "C" void kernel_launch(void* const* d_in, const int* in_sizes, int n_in,
                              void* d_out, int out_size, void* d_ws, size_t ws_size,
                              hipStream_t stream){
  (void)in_sizes;(void)n_in;(void)out_size;
  const float* xin =(const float*)d_in[0];
  const float* ln1g=(const float*)d_in[1];
  const float* ln1b=(const float*)d_in[2];
  const float* ln2g=(const float*)d_in[3];
  const float* ln2b=(const float*)d_in[4];
  const float* Wq=(const float*)d_in[5];
  const float* bq=(const float*)d_in[6];
  const float* Wk=(const float*)d_in[7];
  const float* bk=(const float*)d_in[8];
  const float* Wv=(const float*)d_in[9];
  const float* bv=(const float*)d_in[10];
  const float* Wo=(const float*)d_in[11];
  const float* bo=(const float*)d_in[12];
  const float* proj=(const float*)d_in[13];
  const float* W1=(const float*)d_in[14];
  const float* b1=(const float*)d_in[15];
  const float* W2=(const float*)d_in[16];
  const float* b2=(const float*)d_in[17];
  float* xout=(float*)d_out;

  // diagnostic fallback: if ws too small, emit input copy (absmax-fail, not crash)
  copy_f32<<<(TOK*DIMX/4)/256,256,0,stream>>>((const float4*)xin,(float4*)xout, TOK*DIMX/4);
  if(ws_size < WS_END) return;

  char* ws=(char*)d_ws;
  u16* ybuf =(u16*)(ws+O_Y);
  u16* qbuf =(u16*)(ws+O_Q);
  u16* kbuf =(u16*)(ws+O_K);
  u16* vtb  =(u16*)(ws+O_VT);
  float* partb=(float*)(ws+O_PART);
  u16* ctxtb=(u16*)(ws+O_CTXT);
  float* ksumb=(float*)(ws+O_KSUM);
  float* maxb=(float*)(ws+O_MAX);
  float* vsumb=(float*)(ws+O_VSUM);
  float* csb=(float*)(ws+O_CS);
  u16* wqt=(u16*)(ws+O_WQT); u16* wkt=(u16*)(ws+O_WKT);
  u16* wvt=(u16*)(ws+O_WVT); u16* wot=(u16*)(ws+O_WOT);
  u16* w1t=(u16*)(ws+O_W1T); u16* w2t=(u16*)(ws+O_W2T);
  u16* pjb=(u16*)(ws+O_PJ);
  u16* hbuf=(u16*)(ws+O_Q);   // FF hidden chunk (64 MiB) reuses dead q+k regions

  for(int l=0;l<2;l++){
    size_t wo=(size_t)l*DIMX*DIMX;
    convT<<<dim3(16,16),dim3(32,8),0,stream>>>(Wq+wo, wqt+wo, DIMX, DIMX);
    convT<<<dim3(16,16),dim3(32,8),0,stream>>>(Wk+wo, wkt+wo, DIMX, DIMX);
    convT<<<dim3(16,16),dim3(32,8),0,stream>>>(Wv+wo, wvt+wo, DIMX, DIMX);
    convT<<<dim3(16,16),dim3(32,8),0,stream>>>(Wo+wo, wot+wo, DIMX, DIMX);
    size_t w1o=(size_t)l*DIMX*FFD;
    convT<<<dim3(64,16),dim3(32,8),0,stream>>>(W1+w1o, w1t+w1o, DIMX, FFD);
    convT<<<dim3(16,64),dim3(32,8),0,stream>>>(W2+w1o, w2t+w1o, FFD, DIMX);
  }
  conv_proj<<<(2*NBFX*DHEAD)/256,256,0,stream>>>(proj, pjb, 2*NBFX*DHEAD);
  fill_vt<<<(NBH*16*SEQ)/256,256,0,stream>>>(vtb);

  for(int l=0;l<2;l++){
    const u16* wqt_l=wqt+(size_t)l*DIMX*DIMX;
    const u16* wkt_l=wkt+(size_t)l*DIMX*DIMX;
    const u16* wvt_l=wvt+(size_t)l*DIMX*DIMX;
    const u16* wot_l=wot+(size_t)l*DIMX*DIMX;
    const u16* w1t_l=w1t+(size_t)l*DIMX*FFD;
    const u16* w2t_l=w2t+(size_t)l*DIMX*FFD;
    const u16* pj_l =pjb+(size_t)l*NBFX*DHEAD;

    ln_k<<<TOK,256,0,stream>>>(xout, ln1g+l*DIMX, ln1b+l*DIMX, ybuf);
    gemm_bt<0><<<dim3(4,256),256,0,stream>>>(ybuf, wqt_l, bq+l*DIMX, qbuf, TOK, DIMX, DIMX);
    gemm_bt<0><<<dim3(4,256),256,0,stream>>>(ybuf, wkt_l, bk+l*DIMX, kbuf, TOK, DIMX, DIMX);
    gemm_bt<3><<<dim3(4,256),256,0,stream>>>(ybuf, wvt_l, bv+l*DIMX, vtb, TOK, DIMX, DIMX);
    vsum_k<<<520,256,0,stream>>>(vtb, vsumb);
    kctx<<<dim3(NCHUNK,2,32),256,0,stream>>>(kbuf, pj_l, vtb, partb, maxb);
    ctx_reduce<<<dim3(8,32),256,0,stream>>>(partb, maxb, vsumb, ctxtb, ksumb);
    csum_k<<<32,256,0,stream>>>(ctxtb, ksumb, csb);
    q_fused<<<dim3(128,32),256,0,stream>>>(qbuf, pj_l, ctxtb, ksumb, csb, ybuf);
    gemm_bt<1><<<dim3(4,256),256,0,stream>>>(ybuf, wot_l, bo+l*DIMX, xout, TOK, DIMX, DIMX);
    ln_k<<<TOK,256,0,stream>>>(xout, ln2g+l*DIMX, ln2b+l*DIMX, ybuf);
    for(int c=0;c<2;c++){
      gemm_bt<2><<<dim3(16,128),256,0,stream>>>(ybuf+(size_t)c*16384*DIMX, w1t_l, b1+l*FFD, hbuf, 16384, FFD, DIMX);
      gemm_bt<1><<<dim3(4,128),256,0,stream>>>(hbuf, w2t_l, b2+l*DIMX, xout+(size_t)c*16384*DIMX, 16384, DIMX, FFD);
    }
  }
}

// Round 4
// 1112.861 us; speedup vs baseline: 1.4950x; 1.1900x over previous
//
#include <hip/hip_runtime.h>
#include <math.h>

#define DIMX 512
#define HEADS 8
#define DHEAD 64
#define NBFX 256
#define FFD 2048
#define NBX 4
#define SEQ 8192
#define TOK (NBX*SEQ)     // 32768 tokens
#define NBH (NBX*HEADS)   // 32 (b,h) pairs
#define VROWS 80          // 64 v-dims + ones row(64) + zeros pad
#define NCHUNK 16         // ctx K-split chunks (512 tokens each)
#define BK 64

typedef unsigned short u16;
typedef __attribute__((ext_vector_type(8))) short short8;
typedef __attribute__((ext_vector_type(4))) float f32x4;

__device__ __forceinline__ float bf2f(u16 x){ return __uint_as_float(((unsigned)x)<<16); }
__device__ __forceinline__ u16 f2bf(float f){
  unsigned u=__float_as_uint(f);
  return (u16)((u + 0x7FFFu + ((u>>16)&1u))>>16);
}
__device__ __forceinline__ void gload16(const void* g, void* l){
  __builtin_amdgcn_global_load_lds((const __attribute__((address_space(1))) void*)g,
                                   (__attribute__((address_space(3))) void*)l, 16, 0, 0);
}

#define FENCE asm volatile(""::: "memory")
#define BAR() do{ __builtin_amdgcn_sched_barrier(0); FENCE; __builtin_amdgcn_s_barrier(); FENCE; __builtin_amdgcn_sched_barrier(0);}while(0)

// ---------------- prep / elementwise ----------------
__global__ void copy_f32(const float4* __restrict__ s, float4* __restrict__ d, int n4){
  int i=blockIdx.x*blockDim.x+threadIdx.x;
  if(i<n4) d[i]=s[i];
}
__global__ void conv_proj(const float* __restrict__ p, u16* __restrict__ o, int n){
  int i=blockIdx.x*blockDim.x+threadIdx.x;
  if(i<n) o[i]=f2bf(p[i]*0.35355339059327373f); // fold d^-0.25 into proj
}
// src fp32 [K][Ncol] -> dst bf16 [Ncol][K] (transposed)
__global__ void convT(const float* __restrict__ src, u16* __restrict__ dst, int K, int Ncol){
  __shared__ float t[32][33];
  int k0=blockIdx.y*32, n0=blockIdx.x*32;
  int tx=threadIdx.x, ty=threadIdx.y;
  for(int i=ty;i<32;i+=8) t[i][tx]=src[(size_t)(k0+i)*Ncol + n0+tx];
  __syncthreads();
  for(int i=ty;i<32;i+=8) dst[(size_t)(n0+i)*K + k0+tx]=f2bf(t[tx][i]);
}
__global__ void fill_vt(u16* __restrict__ vt){
  int i=blockIdx.x*blockDim.x+threadIdx.x; // < NBH*16*SEQ = 2^22
  int n=i&(SEQ-1); int r=(i>>13)&15; int bh=i>>17;
  vt[((size_t)bh*VROWS + 64 + r)*SEQ + n] = (r==0)? (u16)0x3F80 : (u16)0;
}
__global__ void pack_bias(const float* __restrict__ bq, const float* __restrict__ bk,
                          const float* __restrict__ bv, float* __restrict__ o){
  int i=blockIdx.x*blockDim.x+threadIdx.x; // 2*1536
  int l=i/1536, c=i-l*1536;
  const float* s=(c<512)? bq : ((c<1024)? bk : bv);
  o[i]=s[l*512 + (c&511)];
}

__global__ __launch_bounds__(256) void ln_k(const float* __restrict__ x, const float* __restrict__ g,
                                            const float* __restrict__ b, u16* __restrict__ y){
  int row=blockIdx.x, t=threadIdx.x;
  const float* xr=x+(size_t)row*DIMX;
  float2 v=*(const float2*)&xr[t*2];
  float s=v.x+v.y;
  #pragma unroll
  for(int m=1;m<64;m<<=1) s+=__shfl_xor(s,m);
  __shared__ float red[8];
  if((t&63)==0) red[t>>6]=s;
  __syncthreads();
  float mean=(red[0]+red[1]+red[2]+red[3])*(1.0f/DIMX);
  float dx=v.x-mean, dy=v.y-mean;
  float s2=dx*dx+dy*dy;
  #pragma unroll
  for(int m=1;m<64;m<<=1) s2+=__shfl_xor(s2,m);
  if((t&63)==0) red[4+(t>>6)]=s2;
  __syncthreads();
  float var=(red[4]+red[5]+red[6]+red[7])*(1.0f/DIMX);
  float rs=rsqrtf(var+1e-5f);
  u16* yr=y+(size_t)row*DIMX;
  yr[t*2  ]=f2bf(dx*rs*g[t*2  ]+b[t*2  ]);
  yr[t*2+1]=f2bf(dy*rs*g[t*2+1]+b[t*2+1]);
}

// ---------------- 256x256 8-phase pipelined bf16 GEMM ----------------
// C = A[M,K] * Bt[N,K]^T + bias.  EPI 0: QKV (q/k bf16 + vT); 1: fp32 +=; 2: gelu->bf16
// 512 thr (8 waves, 2x4), BK=64, double-buffered LDS with granule XOR-swizzle,
// counted vmcnt(4) once per K-tile, setprio around MFMA clusters.
#define MFMA16(MH,BF,NH) do{                                                             \
  __builtin_amdgcn_s_setprio(1);                                                         \
  _Pragma("unroll") for(int kk_=0;kk_<2;kk_++)                                           \
    _Pragma("unroll") for(int i_=0;i_<4;i_++)                                            \
      _Pragma("unroll") for(int j_=0;j_<2;j_++)                                          \
        acc[MH][i_][NH][j_]=__builtin_amdgcn_mfma_f32_16x16x32_bf16(af[i_][kk_],BF[j_][kk_],acc[MH][i_][NH][j_],0,0,0); \
  __builtin_amdgcn_s_setprio(0);                                                         \
}while(0)

template<int EPI>
__global__ __launch_bounds__(512,2) void gemm256(const u16* __restrict__ A, const u16* __restrict__ Bt,
                                                 const float* __restrict__ bias, void* __restrict__ outp,
                                                 u16* __restrict__ out2,
                                                 int M, int Ncol, int K){
  __shared__ u16 lds[2][2][256][64];   // [buf][A=0/B=1][row][col(swizzled granules)]
  const int tid=threadIdx.x, wv=tid>>6, ln=tid&63;
  const int wr=wv>>2, wc=wv&3;          // 2 x 4 wave grid
  const int m0=blockIdx.y*256, n0=blockIdx.x*256;
  const int nt=K/BK;
  f32x4 acc[2][4][2][2]={};             // [mh][i][nh][j]

  auto stage=[&](int t,int half,int isB){
    if(t>=nt) return;
    const u16* src=isB? Bt:A;
    const int b0=isB? n0:m0;
    u16* hb=&lds[t&1][isB][half*128][0];
    #pragma unroll
    for(int s=0;s<2;s++){
      int G=s*512+wv*64+ln;
      int arow=half*128+(G>>3), g=G&7;
      gload16(src+(size_t)(b0+arow)*K + (size_t)t*BK + ((g^(arow&7))<<3),
              hb + (size_t)(s*512+wv*64)*8);
    }
  };
  auto ldA=[&](short8 (&a)[4][2], int buf, int mh){
    #pragma unroll
    for(int i=0;i<4;i++){
      int row=wr*128+mh*64+i*16+(ln&15);
      #pragma unroll
      for(int kk=0;kk<2;kk++)
        a[i][kk]=*(const short8*)&lds[buf][0][row][((kk*4+(ln>>4))^(row&7))<<3];
    }
  };
  auto ldB=[&](short8 (&b)[2][2], int buf, int nh){
    #pragma unroll
    for(int j=0;j<2;j++){
      int row=wc*64+nh*32+j*16+(ln&15);
      #pragma unroll
      for(int kk=0;kk<2;kk++)
        b[j][kk]=*(const short8*)&lds[buf][1][row][((kk*4+(ln>>4))^(row&7))<<3];
    }
  };

  // prologue: tile0 fully + tile1's A0,B0
  stage(0,0,0); stage(0,1,0); stage(0,0,1); stage(0,1,1);
  stage(1,0,1); stage(1,0,0);
  asm volatile("s_waitcnt vmcnt(4)":::"memory");
  BAR();

  for(int t=0;t<nt;t++){
    const int buf=t&1;
    short8 af[4][2], bf0[2][2], bf1[2][2];
    // phase (0,0)
    ldB(bf0,buf,0); ldA(af,buf,0);
    stage(t+1,1,0);                 // A1 of t+1 -> other buf
    BAR();
    MFMA16(0,bf0,0);
    BAR();
    // phase (0,1)
    ldB(bf1,buf,1);
    stage(t+1,1,1);                 // B1 of t+1
    BAR();
    MFMA16(0,bf1,1);
    BAR();
    // phase (1,0)
    ldA(af,buf,1);
    stage(t+2,0,1);                 // B0 of t+2 -> this buf (freed)
    BAR();
    MFMA16(1,bf0,0);
    BAR();
    // phase (1,1)
    stage(t+2,0,0);                 // A0 of t+2
    BAR();
    MFMA16(1,bf1,1);
    if(t+2<nt) asm volatile("s_waitcnt vmcnt(4)":::"memory");
    else       asm volatile("s_waitcnt vmcnt(0)":::"memory");
    BAR();
  }

  // epilogue
  #pragma unroll
  for(int mh=0;mh<2;mh++)
  #pragma unroll
  for(int i=0;i<4;i++)
  #pragma unroll
  for(int nh=0;nh<2;nh++)
  #pragma unroll
  for(int j=0;j<2;j++){
    const int row=m0+wr*128+mh*64+i*16+(ln>>4)*4;
    const int col=n0+wc*64+nh*32+j*16+(ln&15);
    const float bv=bias[col];
    const f32x4 a=acc[mh][i][nh][j];
    if constexpr(EPI==0){
      if(col<1024){ // q (region 0) / k (region 1), row-major [TOK][512]
        u16* o=(u16*)outp + (size_t)(col>>9)*TOK*DIMX + (col&511);
        #pragma unroll
        for(int r=0;r<4;r++) o[(size_t)(row+r)*DIMX]=f2bf(a[r]+bv);
      } else {      // vT[b,h,d,n] transposed write, 4 tokens packed
        const int hd=col-1024, h_=hd>>6, d_=hd&63, b_=row>>13, nn=row&(SEQ-1);
        u16 pk[4];
        #pragma unroll
        for(int r=0;r<4;r++) pk[r]=f2bf(a[r]+bv);
        uint2 pv; pv.x=(unsigned)pk[0]|((unsigned)pk[1]<<16); pv.y=(unsigned)pk[2]|((unsigned)pk[3]<<16);
        *(uint2*)&out2[((size_t)(b_*HEADS+h_)*VROWS+d_)*SEQ+nn]=pv;
      }
    } else if constexpr(EPI==1){
      float* o=(float*)outp;
      #pragma unroll
      for(int r=0;r<4;r++){ size_t ix=(size_t)(row+r)*Ncol+col; o[ix]+=a[r]+bv; }
    } else {
      u16* o=(u16*)outp;
      #pragma unroll
      for(int r=0;r<4;r++){
        float v=a[r]+bv;
        v=0.5f*v*(1.0f+erff(v*0.70710678118654752f)); // exact GELU
        o[(size_t)(row+r)*Ncol+col]=f2bf(v);
      }
    }
  }
}

// ---------------- vsum: per (bh,d<=64) row-sum of vT over all n ----------------
__global__ __launch_bounds__(256) void vsum_k(const u16* __restrict__ vt, float* __restrict__ vs){
  const int gw=blockIdx.x*4 + (threadIdx.x>>6); // 0..2079 = 32*65
  const int ln=threadIdx.x&63;
  const int bh=gw/65, d=gw-bh*65;
  const u16* row=vt+((size_t)bh*VROWS+d)*SEQ;
  float s=0;
  for(int it=0;it<16;it++){
    short8 v=*(const short8*)&row[it*512+ln*8];
    #pragma unroll
    for(int e=0;e<8;e++) s+=bf2f((u16)v[e]);
  }
  #pragma unroll
  for(int m=1;m<64;m<<=1) s+=__shfl_xor(s,m);
  if(ln==0) vs[bh*80+d]=s;
}

// ---------------- fused k-features + ctx partial GEMM (deferred max) ----------------
__global__ __launch_bounds__(256) void kctx(const u16* __restrict__ kb, const u16* __restrict__ pj,
                                            const u16* __restrict__ vt,
                                            float* __restrict__ part, float* __restrict__ maxb){
  __shared__ u16 kl[64*64];     // [token][d], granule-swizzled by token&7
  __shared__ u16 vl[80*64];     // [d][n],     granule-swizzled by d&7
  __shared__ u16 kp_l[128*64];  // [m_local][n], granule-swizzled by m&7 (per-wave rows)
  __shared__ float dgl[64];
  const int kc=blockIdx.x, half=blockIdx.y, bh=blockIdx.z, b_=bh>>3, h_=bh&7;
  const int tid=threadIdx.x, wv=tid>>6, ln=tid&63;
  short8 pjf[2][2];
  #pragma unroll
  for(int i=0;i<2;i++)
    #pragma unroll
    for(int t=0;t<2;t++)
      pjf[i][t]=*(const short8*)&pj[(size_t)(half*128+wv*32+i*16+(ln&15))*DHEAD + t*32 + (ln>>4)*8];
  f32x4 ctx[2][5]={};
  float m_run=-3.0e38f;
  const u16* vbh=vt+(size_t)bh*VROWS*SEQ;
  for(int s=0;s<8;s++){
    const int n0s=kc*512+s*64;
    const u16* kg=kb+((size_t)(b_*SEQ+n0s))*DIMX + h_*DHEAD;
    #pragma unroll
    for(int cc=0;cc<2;cc++){
      int c=cc*256+wv*64+ln; int t=c>>3, g=c&7;
      gload16(kg+(size_t)t*DIMX+((g^(t&7))*8), &kl[(size_t)(cc*256+wv*64)*8]);
    }
    #pragma unroll
    for(int cc=0;cc<2;cc++){
      int c=cc*256+wv*64+ln; int d=c>>3, g=c&7;
      gload16(vbh+(size_t)d*SEQ+n0s+((g^(d&7))*8), &vl[(size_t)(cc*256+wv*64)*8]);
    }
    if(wv<2){
      int c=512+wv*64+ln; int d=c>>3, g=c&7;
      gload16(vbh+(size_t)d*SEQ+n0s+((g^(d&7))*8), &vl[(size_t)(512+wv*64)*8]);
    }
    __syncthreads();
    if(tid<64){
      float ss=0;
      #pragma unroll
      for(int gg=0;gg<8;gg++){
        short8 kv=*(const short8*)&kl[tid*64 + ((gg+tid)&7)*8];
        #pragma unroll
        for(int e=0;e<8;e++){ float x=bf2f((u16)kv[e]); ss+=x*x; }
      }
      dgl[tid]=ss*0.0625f; // 0.5 * d^-0.5
    }
    __syncthreads();
    f32x4 dd[2][4]={};
    #pragma unroll
    for(int tk=0;tk<2;tk++)
      #pragma unroll
      for(int j=0;j<4;j++){
        short8 bk_=*(const short8*)&kl[(j*16+(ln&15))*64 + (((tk*4+(ln>>4))^(ln&7))<<3)];
        #pragma unroll
        for(int i=0;i<2;i++)
          dd[i][j]=__builtin_amdgcn_mfma_f32_16x16x32_bf16(pjf[i][tk],bk_,dd[i][j],0,0,0);
      }
    float mt=-3.0e38f;
    #pragma unroll
    for(int i=0;i<2;i++)
      #pragma unroll
      for(int j=0;j<4;j++)
        #pragma unroll
        for(int r=0;r<4;r++) mt=fmaxf(mt,dd[i][j][r]);
    #pragma unroll
    for(int m=1;m<64;m<<=1) mt=fmaxf(mt,__shfl_xor(mt,m));
    if(mt>m_run){
      float sc=__expf(m_run-mt);
      #pragma unroll
      for(int i=0;i<2;i++)
        #pragma unroll
        for(int j2=0;j2<5;j2++) ctx[i][j2]*=sc;
      m_run=mt;
    }
    #pragma unroll
    for(int j=0;j<4;j++){
      const float dgn=dgl[j*16+(ln&15)];
      #pragma unroll
      for(int i=0;i<2;i++)
        #pragma unroll
        for(int r=0;r<4;r++){
          int m_l=wv*32+i*16+(ln>>4)*4+r;
          float E=__expf(dd[i][j][r]-dgn-m_run);
          kp_l[m_l*64 + (((j*2+((ln>>3)&1))^(m_l&7))<<3) + (ln&7)]=f2bf(E);
        }
    }
    #pragma unroll
    for(int tk=0;tk<2;tk++){
      short8 af2[2];
      #pragma unroll
      for(int i=0;i<2;i++)
        af2[i]=*(const short8*)&kp_l[(wv*32+i*16+(ln&15))*64 + (((tk*4+(ln>>4))^(ln&7))<<3)];
      #pragma unroll
      for(int j2=0;j2<5;j2++){
        short8 bf2=*(const short8*)&vl[(j2*16+(ln&15))*64 + (((tk*4+(ln>>4))^(ln&7))<<3)];
        #pragma unroll
        for(int i=0;i<2;i++)
          ctx[i][j2]=__builtin_amdgcn_mfma_f32_16x16x32_bf16(af2[i],bf2,ctx[i][j2],0,0,0);
      }
    }
    __syncthreads();
  }
  float* po=part + ((size_t)(bh*NCHUNK+kc))*(256*80) + (size_t)half*128*80;
  #pragma unroll
  for(int i=0;i<2;i++)
    #pragma unroll
    for(int j2=0;j2<5;j2++)
      #pragma unroll
      for(int r=0;r<4;r++)
        po[(size_t)(wv*32+i*16+(ln>>4)*4+r)*80 + j2*16+(ln&15)]=ctx[i][j2][r];
  if(ln==0) maxb[bh*128 + kc*8 + half*4 + wv]=m_run;
}

// ---------------- ctx reduce: rescale chunk partials + analytic eps ----------------
__global__ __launch_bounds__(256) void ctx_reduce(const float* __restrict__ part, const float* __restrict__ maxb,
                                                  const float* __restrict__ vs,
                                                  u16* __restrict__ ctxT, float* __restrict__ ksum){
  __shared__ float mx_s[128];
  __shared__ float sc_s[NCHUNK];
  const int mseg=blockIdx.x, bh=blockIdx.y, tid=threadIdx.x;
  if(tid<128) mx_s[tid]=maxb[(size_t)bh*128+tid];
  __syncthreads();
  float km=-3.0e38f;
  for(int i=0;i<128;i++) km=fmaxf(km,mx_s[i]);
  const int m0=mseg*32;
  const int half=m0>>7, wvv=(m0&127)>>5;
  if(tid<NCHUNK) sc_s[tid]=__expf(mx_s[tid*8+half*4+wvv]-km);
  __syncthreads();
  for(int rep=0;rep<10;rep++){
    int idx=rep*256+tid;           // 0..2559 = 32*80
    int mo=idx/80, d=idx-mo*80;
    int m=m0+mo;
    float s=0;
    #pragma unroll
    for(int c=0;c<NCHUNK;c++)
      s+=sc_s[c]*part[((size_t)(bh*NCHUNK+c))*(256*80) + (size_t)m*80 + d];
    float vsd=(d<=64)? vs[bh*80+d] : 0.0f;
    float val=0.0625f*(s + 1e-4f*vsd);
    if(d<64)       ctxT[((size_t)bh*64+d)*NBFX + m]=f2bf(val);
    else if(d==64) ksum[bh*NBFX+m]=val;
  }
}

// ---------------- column sums of ctxT / ksum ----------------
__global__ void csum_k(const u16* __restrict__ ctxT, const float* __restrict__ ksum, float* __restrict__ cs){
  const int bh=blockIdx.x, t=threadIdx.x;
  if(t<64){
    const u16* r=ctxT+((size_t)bh*64+t)*NBFX;
    float s=0;
    for(int m=0;m<NBFX;m+=8){
      short8 v=*(const short8*)&r[m];
      #pragma unroll
      for(int e=0;e<8;e++) s+=bf2f((u16)v[e]);
    }
    cs[bh*80+t]=s;
  } else if(t==64){
    float s=0;
    for(int m=0;m<NBFX;m++) s+=ksum[bh*NBFX+m];
    cs[bh*80+64]=s;
  }
}

// ---------------- fused query path (no-max E-form) ----------------
__global__ __launch_bounds__(256) void q_fused(const u16* __restrict__ qb, const u16* __restrict__ pj,
                                               const u16* __restrict__ ctxT, const float* __restrict__ ksum,
                                               const float* __restrict__ cs, u16* __restrict__ ob){
  __shared__ u16 ql[64*64];
  __shared__ u16 qpl[64*136];
  __shared__ float dgs[64];
  __shared__ float mred[4*64], dred[4*64];
  __shared__ float ff_s[64], dinv_s[64];
  const int bh=blockIdx.y, b_=bh>>3, h_=bh&7;
  const int n0=blockIdx.x*64;
  const int tid=threadIdx.x, wv=tid>>6, ln=tid&63;
  const u16* qg=qb+((size_t)(b_*SEQ+n0))*DIMX + h_*DHEAD;
  #pragma unroll
  for(int cc=0;cc<2;cc++){
    int c=cc*256+wv*64+ln; int t=c>>3, g=c&7;
    gload16(qg+(size_t)t*DIMX+((g^(t&7))*8), &ql[(size_t)(cc*256+wv*64)*8]);
  }
  short8 pjf[2][2][2];
  float ks[2][2][4];
  #pragma unroll
  for(int h=0;h<2;h++)
    #pragma unroll
    for(int i=0;i<2;i++){
      #pragma unroll
      for(int t=0;t<2;t++)
        pjf[h][i][t]=*(const short8*)&pj[(size_t)(h*128+wv*32+i*16+(ln&15))*DHEAD + t*32 + (ln>>4)*8];
      #pragma unroll
      for(int r=0;r<4;r++)
        ks[h][i][r]=ksum[bh*NBFX + h*128+wv*32+i*16+(ln>>4)*4+r];
    }
  const float KS=cs[bh*80+64];
  __syncthreads();
  if(tid<64){
    float ss=0;
    #pragma unroll
    for(int gg=0;gg<8;gg++){
      short8 kv=*(const short8*)&ql[tid*64 + ((gg+tid)&7)*8];
      #pragma unroll
      for(int e=0;e<8;e++){ float x=bf2f((u16)kv[e]); ss+=x*x; }
    }
    dgs[tid]=ss*0.0625f;
  }
  __syncthreads();
  float mxp[4]={-3.0e38f,-3.0e38f,-3.0e38f,-3.0e38f};
  float dnp[4]={0,0,0,0};
  f32x4 oc[4]={};
  const u16* cb=ctxT+(size_t)bh*64*NBFX;
  #pragma unroll
  for(int h=0;h<2;h++){
    #pragma unroll
    for(int j=0;j<4;j++){
      f32x4 dq[2]={};
      #pragma unroll
      for(int tk=0;tk<2;tk++){
        short8 bq=*(const short8*)&ql[(j*16+(ln&15))*64 + (((tk*4+(ln>>4))^(ln&7))<<3)];
        #pragma unroll
        for(int i=0;i<2;i++)
          dq[i]=__builtin_amdgcn_mfma_f32_16x16x32_bf16(pjf[h][i][tk],bq,dq[i],0,0,0);
      }
      const float dgn=dgs[j*16+(ln&15)];
      #pragma unroll
      for(int i=0;i<2;i++)
        #pragma unroll
        for(int r=0;r<4;r++){
          float d_=dq[i][r];
          mxp[j]=fmaxf(mxp[j],d_);
          float E=__expf(d_-dgn);
          dnp[j]+=E*ks[h][i][r];
          qpl[(j*16+(ln&15))*136 + wv*32+i*16+(ln>>4)*4+r]=f2bf(E);
        }
    }
    __syncthreads();
    #pragma unroll
    for(int mk2=0;mk2<4;mk2++){
      short8 aq=*(const short8*)&cb[(size_t)(wv*16+(ln&15))*NBFX + h*128 + mk2*32 + (ln>>4)*8];
      #pragma unroll
      for(int j2=0;j2<4;j2++){
        short8 bqp=*(const short8*)&qpl[(j2*16+(ln&15))*136 + mk2*32 + (ln>>4)*8];
        oc[j2]=__builtin_amdgcn_mfma_f32_16x16x32_bf16(aq,bqp,oc[j2],0,0,0);
      }
    }
    __syncthreads();
  }
  #pragma unroll
  for(int j=0;j<4;j++){
    #pragma unroll
    for(int msk=16;msk<64;msk<<=1){
      mxp[j]=fmaxf(mxp[j],__shfl_xor(mxp[j],msk));
      dnp[j]+=__shfl_xor(dnp[j],msk);
    }
  }
  if(ln<16){
    #pragma unroll
    for(int j=0;j<4;j++){ mred[wv*64+j*16+ln]=mxp[j]; dred[wv*64+j*16+ln]=dnp[j]; }
  }
  __syncthreads();
  if(tid<64){
    float mx=fmaxf(fmaxf(mred[tid],mred[64+tid]),fmaxf(mred[128+tid],mred[192+tid]));
    float dn=dred[tid]+dred[64+tid]+dred[128+tid]+dred[192+tid];
    float f=1e-4f*__expf(mx);
    ff_s[tid]=f;
    dinv_s[tid]=1.0f/(dn + f*KS);
  }
  __syncthreads();
  float csr[4];
  #pragma unroll
  for(int r=0;r<4;r++) csr[r]=cs[bh*80 + wv*16+(ln>>4)*4+r];
  u16* og=ob+((size_t)(b_*SEQ+n0))*DIMX + h_*DHEAD;
  #pragma unroll
  for(int j2=0;j2<4;j2++){
    int n=j2*16+(ln&15);
    float f=ff_s[n], di=dinv_s[n];
    u16 pk[4];
    #pragma unroll
    for(int r=0;r<4;r++) pk[r]=f2bf((oc[j2][r]+f*csr[r])*di);
    uint2 pv; pv.x=(unsigned)pk[0]|((unsigned)pk[1]<<16); pv.y=(unsigned)pk[2]|((unsigned)pk[3]<<16);
    *(uint2*)&og[(size_t)n*DIMX + wv*16+(ln>>4)*4]=pv;
  }
}

// ---------------- workspace layout (~190 MiB) ----------------
static constexpr size_t SZ_ACT=(size_t)TOK*DIMX*2;                 // 32 MiB
static constexpr size_t O_Y=0, O_Q=SZ_ACT, O_K=2*SZ_ACT;
static constexpr size_t O_VT=3*SZ_ACT;                             // 96 MiB
static constexpr size_t SZ_VT=(size_t)NBH*VROWS*SEQ*2;             // 40 MiB
static constexpr size_t O_PART=O_VT+SZ_VT;                         // 136 MiB
static constexpr size_t SZ_PART=(size_t)NBH*NCHUNK*256*80*4;       // 40 MiB
static constexpr size_t O_CTXT=O_PART+SZ_PART;                     // 176 MiB
static constexpr size_t SZ_CTXT=(size_t)NBH*64*NBFX*2;
static constexpr size_t O_KSUM=O_CTXT+SZ_CTXT;
static constexpr size_t SZ_KSUM=(size_t)NBH*NBFX*4;
static constexpr size_t O_MAX=O_KSUM+SZ_KSUM;
static constexpr size_t SZ_MAX=(size_t)NBH*128*4;
static constexpr size_t O_VSUM=O_MAX+SZ_MAX;
static constexpr size_t SZ_VSUM=(size_t)NBH*80*4;
static constexpr size_t O_CS=O_VSUM+SZ_VSUM;
static constexpr size_t SZ_CS=(size_t)NBH*80*4;
static constexpr size_t O_WQKV=O_CS+SZ_CS;
static constexpr size_t SZ_WQKV=(size_t)2*1536*DIMX*2;             // 3 MiB
static constexpr size_t O_WOT=O_WQKV+SZ_WQKV;
static constexpr size_t SZ_W=(size_t)2*DIMX*DIMX*2;                // 1 MiB
static constexpr size_t O_W1T=O_WOT+SZ_W;
static constexpr size_t SZ_W1=(size_t)2*FFD*DIMX*2;                // 4 MiB
static constexpr size_t O_W2T=O_W1T+SZ_W1;
static constexpr size_t O_PJ=O_W2T+SZ_W1;
static constexpr size_t O_QKVB=O_PJ+(size_t)2*NBFX*DHEAD*2;
static constexpr size_t WS_END=O_QKVB+(size_t)2*1536*4;

extern "C" void kernel_launch(void* const* d_in, const int* in_sizes, int n_in,
                              void* d_out, int out_size, void* d_ws, size_t ws_size,
                              hipStream_t stream){
  (void)in_sizes;(void)n_in;(void)out_size;
  const float* xin =(const float*)d_in[0];
  const float* ln1g=(const float*)d_in[1];
  const float* ln1b=(const float*)d_in[2];
  const float* ln2g=(const float*)d_in[3];
  const float* ln2b=(const float*)d_in[4];
  const float* Wq=(const float*)d_in[5];
  const float* bq=(const float*)d_in[6];
  const float* Wk=(const float*)d_in[7];
  const float* bk=(const float*)d_in[8];
  const float* Wv=(const float*)d_in[9];
  const float* bv=(const float*)d_in[10];
  const float* Wo=(const float*)d_in[11];
  const float* bo=(const float*)d_in[12];
  const float* proj=(const float*)d_in[13];
  const float* W1=(const float*)d_in[14];
  const float* b1=(const float*)d_in[15];
  const float* W2=(const float*)d_in[16];
  const float* b2=(const float*)d_in[17];
  float* xout=(float*)d_out;

  copy_f32<<<(TOK*DIMX/4)/256,256,0,stream>>>((const float4*)xin,(float4*)xout, TOK*DIMX/4);
  if(ws_size < WS_END) return;

  char* ws=(char*)d_ws;
  u16* ybuf =(u16*)(ws+O_Y);
  u16* qbuf =(u16*)(ws+O_Q);
  u16* kbuf =(u16*)(ws+O_K);
  u16* vtb  =(u16*)(ws+O_VT);
  float* partb=(float*)(ws+O_PART);
  u16* ctxtb=(u16*)(ws+O_CTXT);
  float* ksumb=(float*)(ws+O_KSUM);
  float* maxb=(float*)(ws+O_MAX);
  float* vsumb=(float*)(ws+O_VSUM);
  float* csb=(float*)(ws+O_CS);
  u16* wqkvt=(u16*)(ws+O_WQKV);
  u16* wot=(u16*)(ws+O_WOT);
  u16* w1t=(u16*)(ws+O_W1T); u16* w2t=(u16*)(ws+O_W2T);
  u16* pjb=(u16*)(ws+O_PJ);
  float* qkvb=(float*)(ws+O_QKVB);
  u16* hbuf=(u16*)(ws+O_Q);   // FF hidden [32768][2048] reuses q/k/vt/part regions

  for(int l=0;l<2;l++){
    size_t wo=(size_t)l*DIMX*DIMX;
    convT<<<dim3(16,16),dim3(32,8),0,stream>>>(Wq+wo, wqkvt+(size_t)(l*1536+   0)*DIMX, DIMX, DIMX);
    convT<<<dim3(16,16),dim3(32,8),0,stream>>>(Wk+wo, wqkvt+(size_t)(l*1536+ 512)*DIMX, DIMX, DIMX);
    convT<<<dim3(16,16),dim3(32,8),0,stream>>>(Wv+wo, wqkvt+(size_t)(l*1536+1024)*DIMX, DIMX, DIMX);
    convT<<<dim3(16,16),dim3(32,8),0,stream>>>(Wo+wo, wot+wo, DIMX, DIMX);
    size_t w1o=(size_t)l*DIMX*FFD;
    convT<<<dim3(64,16),dim3(32,8),0,stream>>>(W1+w1o, w1t+w1o, DIMX, FFD);
    convT<<<dim3(16,64),dim3(32,8),0,stream>>>(W2+w1o, w2t+w1o, FFD, DIMX);
  }
  conv_proj<<<(2*NBFX*DHEAD)/256,256,0,stream>>>(proj, pjb, 2*NBFX*DHEAD);
  pack_bias<<<12,256,0,stream>>>(bq,bk,bv,qkvb);

  for(int l=0;l<2;l++){
    const u16* wqkvt_l=wqkvt+(size_t)l*1536*DIMX;
    const u16* wot_l=wot+(size_t)l*DIMX*DIMX;
    const u16* w1t_l=w1t+(size_t)l*DIMX*FFD;
    const u16* w2t_l=w2t+(size_t)l*DIMX*FFD;
    const u16* pj_l =pjb+(size_t)l*NBFX*DHEAD;
    const float* qkvb_l=qkvb+(size_t)l*1536;

    ln_k<<<TOK,256,0,stream>>>(xout, ln1g+l*DIMX, ln1b+l*DIMX, ybuf);
    fill_vt<<<(NBH*16*SEQ)/256,256,0,stream>>>(vtb);
    gemm256<0><<<dim3(6,128),512,0,stream>>>(ybuf, wqkvt_l, qkvb_l, qbuf, vtb, TOK, 1536, DIMX);
    vsum_k<<<520,256,0,stream>>>(vtb, vsumb);
    kctx<<<dim3(NCHUNK,2,32),256,0,stream>>>(kbuf, pj_l, vtb, partb, maxb);
    ctx_reduce<<<dim3(8,32),256,0,stream>>>(partb, maxb, vsumb, ctxtb, ksumb);
    csum_k<<<32,256,0,stream>>>(ctxtb, ksumb, csb);
    q_fused<<<dim3(128,32),256,0,stream>>>(qbuf, pj_l, ctxtb, ksumb, csb, ybuf);
    gemm256<1><<<dim3(2,128),512,0,stream>>>(ybuf, wot_l, bo+l*DIMX, xout, nullptr, TOK, DIMX, DIMX);
    ln_k<<<TOK,256,0,stream>>>(xout, ln2g+l*DIMX, ln2b+l*DIMX, ybuf);
    gemm256<2><<<dim3(8,128),512,0,stream>>>(ybuf, w1t_l, b1+l*FFD, hbuf, nullptr, TOK, FFD, DIMX);
    gemm256<1><<<dim3(2,128),512,0,stream>>>(hbuf, w2t_l, b2+l*DIMX, xout, nullptr, TOK, DIMX, FFD);
  }
}

// Round 5
// 1054.531 us; speedup vs baseline: 1.5777x; 1.0553x over previous
//
#include <hip/hip_runtime.h>
#include <math.h>

#define DIMX 512
#define HEADS 8
#define DHEAD 64
#define NBFX 256
#define FFD 2048
#define NBX 4
#define SEQ 8192
#define TOK (NBX*SEQ)     // 32768 tokens
#define NBH (NBX*HEADS)   // 32 (b,h) pairs
#define VROWS 80          // 64 v-dims + ones row(64) + zeros pad
#define NCHUNK 16         // ctx K-split chunks (512 tokens each)
#define BK 64

typedef unsigned short u16;
typedef __attribute__((ext_vector_type(8))) short short8;
typedef __attribute__((ext_vector_type(4))) float f32x4;

__device__ __forceinline__ float bf2f(u16 x){ return __uint_as_float(((unsigned)x)<<16); }
__device__ __forceinline__ u16 f2bf(float f){
  unsigned u=__float_as_uint(f);
  return (u16)((u + 0x7FFFu + ((u>>16)&1u))>>16);
}
__device__ __forceinline__ void gload16(const void* g, void* l){
  __builtin_amdgcn_global_load_lds((const __attribute__((address_space(1))) void*)g,
                                   (__attribute__((address_space(3))) void*)l, 16, 0, 0);
}

#define FENCE asm volatile(""::: "memory")
#define BAR() do{ __builtin_amdgcn_sched_barrier(0); FENCE; __builtin_amdgcn_s_barrier(); FENCE; __builtin_amdgcn_sched_barrier(0);}while(0)

// ---------------- prep / elementwise ----------------
__global__ void copy_f32(const float4* __restrict__ s, float4* __restrict__ d, int n4){
  int i=blockIdx.x*blockDim.x+threadIdx.x;
  if(i<n4) d[i]=s[i];
}
__global__ void conv_proj(const float* __restrict__ p, u16* __restrict__ o, int n){
  int i=blockIdx.x*blockDim.x+threadIdx.x;
  if(i<n) o[i]=f2bf(p[i]*0.35355339059327373f); // fold d^-0.25 into proj
}
// src fp32 [K][Ncol] -> dst bf16 [Ncol][K] (transposed)
__global__ void convT(const float* __restrict__ src, u16* __restrict__ dst, int K, int Ncol){
  __shared__ float t[32][33];
  int k0=blockIdx.y*32, n0=blockIdx.x*32;
  int tx=threadIdx.x, ty=threadIdx.y;
  for(int i=ty;i<32;i+=8) t[i][tx]=src[(size_t)(k0+i)*Ncol + n0+tx];
  __syncthreads();
  for(int i=ty;i<32;i+=8) dst[(size_t)(n0+i)*K + k0+tx]=f2bf(t[tx][i]);
}
__global__ void fill_vt(u16* __restrict__ vt){
  int i=blockIdx.x*blockDim.x+threadIdx.x; // < NBH*16*SEQ = 2^22
  int n=i&(SEQ-1); int r=(i>>13)&15; int bh=i>>17;
  vt[((size_t)bh*VROWS + 64 + r)*SEQ + n] = (r==0)? (u16)0x3F80 : (u16)0;
}
__global__ void pack_bias(const float* __restrict__ bq, const float* __restrict__ bk,
                          const float* __restrict__ bv, float* __restrict__ o){
  int i=blockIdx.x*blockDim.x+threadIdx.x; // 2*1536
  int l=i/1536, c=i-l*1536;
  const float* s=(c<512)? bq : ((c<1024)? bk : bv);
  o[i]=s[l*512 + (c&511)];
}

// wave-per-row LN: 4 rows/block, no LDS/barriers
__global__ __launch_bounds__(256) void ln_k(const float* __restrict__ x, const float* __restrict__ g,
                                            const float* __restrict__ b, u16* __restrict__ y){
  const int row=blockIdx.x*4 + (threadIdx.x>>6);
  const int ln=threadIdx.x&63;
  const float* xr=x+(size_t)row*DIMX;
  float4 v0=*(const float4*)&xr[ln*8];
  float4 v1=*(const float4*)&xr[ln*8+4];
  float v[8]={v0.x,v0.y,v0.z,v0.w,v1.x,v1.y,v1.z,v1.w};
  float s=0;
  #pragma unroll
  for(int e=0;e<8;e++) s+=v[e];
  #pragma unroll
  for(int m=1;m<64;m<<=1) s+=__shfl_xor(s,m);
  const float mean=s*(1.0f/DIMX);
  float s2=0;
  #pragma unroll
  for(int e=0;e<8;e++){ v[e]-=mean; s2+=v[e]*v[e]; }
  #pragma unroll
  for(int m=1;m<64;m<<=1) s2+=__shfl_xor(s2,m);
  const float rs=rsqrtf(s2*(1.0f/DIMX)+1e-5f);
  u16* yr=y+(size_t)row*DIMX+ln*8;
  u16 pk[8];
  #pragma unroll
  for(int e=0;e<8;e++) pk[e]=f2bf(v[e]*rs*g[ln*8+e]+b[ln*8+e]);
  uint4 pv;
  pv.x=(unsigned)pk[0]|((unsigned)pk[1]<<16); pv.y=(unsigned)pk[2]|((unsigned)pk[3]<<16);
  pv.z=(unsigned)pk[4]|((unsigned)pk[5]<<16); pv.w=(unsigned)pk[6]|((unsigned)pk[7]<<16);
  *(uint4*)yr=pv;
}

// ---------------- 256x256 8-phase pipelined bf16 GEMM (XCD-band swizzled) ----------------
// C = A[M,K] * Bt[N,K]^T + bias.  EPI 0: QKV (q/k bf16 + vT); 1: fp32 +=; 2: gelu->bf16
#define MFMA16(MH,BF,NH) do{                                                             \
  __builtin_amdgcn_s_setprio(1);                                                         \
  _Pragma("unroll") for(int kk_=0;kk_<2;kk_++)                                           \
    _Pragma("unroll") for(int i_=0;i_<4;i_++)                                            \
      _Pragma("unroll") for(int j_=0;j_<2;j_++)                                          \
        acc[MH][i_][NH][j_]=__builtin_amdgcn_mfma_f32_16x16x32_bf16(af[i_][kk_],BF[j_][kk_],acc[MH][i_][NH][j_],0,0,0); \
  __builtin_amdgcn_s_setprio(0);                                                         \
}while(0)

template<int EPI>
__global__ __launch_bounds__(512,2) void gemm256(const u16* __restrict__ A, const u16* __restrict__ Bt,
                                                 const float* __restrict__ bias, void* __restrict__ outp,
                                                 u16* __restrict__ out2,
                                                 int M, int Ncol, int K){
  __shared__ u16 lds[2][2][256][64];   // [buf][A=0/B=1][row][col(swizzled granules)]
  const int tid=threadIdx.x, wv=tid>>6, ln=tid&63;
  const int wr=wv>>2, wc=wv&3;          // 2 x 4 wave grid
  // XCD-band swizzle: all x-blocks of an A-panel band -> same XCD (requires gy%8==0)
  const int gx=gridDim.x, gy=gridDim.y;
  const int P=blockIdx.y*gx+blockIdx.x;
  const int band=gy>>3;
  const int xcd=P&7, sI=P>>3;
  const int by=xcd*band + (sI - (sI/band)*band);
  const int bx=sI/band;
  const int m0=by*256, n0=bx*256;
  const int nt=K/BK;
  f32x4 acc[2][4][2][2]={};             // [mh][i][nh][j]

  auto stage=[&](int t,int half,int isB){
    if(t>=nt) return;
    const u16* src=isB? Bt:A;
    const int b0=isB? n0:m0;
    u16* hb=&lds[t&1][isB][half*128][0];
    #pragma unroll
    for(int s=0;s<2;s++){
      int G=s*512+wv*64+ln;
      int arow=half*128+(G>>3), g=G&7;
      gload16(src+(size_t)(b0+arow)*K + (size_t)t*BK + ((g^(arow&7))<<3),
              hb + (size_t)(s*512+wv*64)*8);
    }
  };
  auto ldA=[&](short8 (&a)[4][2], int buf, int mh){
    #pragma unroll
    for(int i=0;i<4;i++){
      int row=wr*128+mh*64+i*16+(ln&15);
      #pragma unroll
      for(int kk=0;kk<2;kk++)
        a[i][kk]=*(const short8*)&lds[buf][0][row][((kk*4+(ln>>4))^(row&7))<<3];
    }
  };
  auto ldB=[&](short8 (&b)[2][2], int buf, int nh){
    #pragma unroll
    for(int j=0;j<2;j++){
      int row=wc*64+nh*32+j*16+(ln&15);
      #pragma unroll
      for(int kk=0;kk<2;kk++)
        b[j][kk]=*(const short8*)&lds[buf][1][row][((kk*4+(ln>>4))^(row&7))<<3];
    }
  };

  // prologue: tile0 fully + tile1's A0,B0
  stage(0,0,0); stage(0,1,0); stage(0,0,1); stage(0,1,1);
  stage(1,0,1); stage(1,0,0);
  asm volatile("s_waitcnt vmcnt(4)":::"memory");
  BAR();

  for(int t=0;t<nt;t++){
    const int buf=t&1;
    short8 af[4][2], bf0[2][2], bf1[2][2];
    // phase (0,0)
    ldB(bf0,buf,0); ldA(af,buf,0);
    stage(t+1,1,0);                 // A1 of t+1 -> other buf
    BAR();
    MFMA16(0,bf0,0);
    BAR();
    // phase (0,1)
    ldB(bf1,buf,1);
    stage(t+1,1,1);                 // B1 of t+1
    BAR();
    MFMA16(0,bf1,1);
    BAR();
    // phase (1,0)
    ldA(af,buf,1);
    stage(t+2,0,1);                 // B0 of t+2 -> this buf (freed)
    BAR();
    MFMA16(1,bf0,0);
    BAR();
    // phase (1,1)
    stage(t+2,0,0);                 // A0 of t+2
    BAR();
    MFMA16(1,bf1,1);
    if(t+2<nt) asm volatile("s_waitcnt vmcnt(4)":::"memory");
    else       asm volatile("s_waitcnt vmcnt(0)":::"memory");
    BAR();
  }

  // epilogue
  #pragma unroll
  for(int mh=0;mh<2;mh++)
  #pragma unroll
  for(int i=0;i<4;i++)
  #pragma unroll
  for(int nh=0;nh<2;nh++)
  #pragma unroll
  for(int j=0;j<2;j++){
    const int row=m0+wr*128+mh*64+i*16+(ln>>4)*4;
    const int col=n0+wc*64+nh*32+j*16+(ln&15);
    const float bv=bias[col];
    const f32x4 a=acc[mh][i][nh][j];
    if constexpr(EPI==0){
      if(col<1024){ // q (region 0) / k (region 1), row-major [TOK][512]
        u16* o=(u16*)outp + (size_t)(col>>9)*TOK*DIMX + (col&511);
        #pragma unroll
        for(int r=0;r<4;r++) o[(size_t)(row+r)*DIMX]=f2bf(a[r]+bv);
      } else {      // vT[b,h,d,n] transposed write, 4 tokens packed
        const int hd=col-1024, h_=hd>>6, d_=hd&63, b_=row>>13, nn=row&(SEQ-1);
        u16 pk[4];
        #pragma unroll
        for(int r=0;r<4;r++) pk[r]=f2bf(a[r]+bv);
        uint2 pv; pv.x=(unsigned)pk[0]|((unsigned)pk[1]<<16); pv.y=(unsigned)pk[2]|((unsigned)pk[3]<<16);
        *(uint2*)&out2[((size_t)(b_*HEADS+h_)*VROWS+d_)*SEQ+nn]=pv;
      }
    } else if constexpr(EPI==1){
      float* o=(float*)outp;
      #pragma unroll
      for(int r=0;r<4;r++){ size_t ix=(size_t)(row+r)*Ncol+col; o[ix]+=a[r]+bv; }
    } else {
      u16* o=(u16*)outp;
      #pragma unroll
      for(int r=0;r<4;r++){
        float v=a[r]+bv;
        v=0.5f*v*(1.0f+erff(v*0.70710678118654752f)); // exact GELU
        o[(size_t)(row+r)*Ncol+col]=f2bf(v);
      }
    }
  }
}

// ---------------- vsum: per (bh,d<=64) row-sum of vT over all n ----------------
__global__ __launch_bounds__(256) void vsum_k(const u16* __restrict__ vt, float* __restrict__ vs){
  const int gw=blockIdx.x*4 + (threadIdx.x>>6); // 0..2079 = 32*65
  const int ln=threadIdx.x&63;
  const int bh=gw/65, d=gw-bh*65;
  const u16* row=vt+((size_t)bh*VROWS+d)*SEQ;
  float s=0;
  for(int it=0;it<16;it++){
    short8 v=*(const short8*)&row[it*512+ln*8];
    #pragma unroll
    for(int e=0;e<8;e++) s+=bf2f((u16)v[e]);
  }
  #pragma unroll
  for(int m=1;m<64;m<<=1) s+=__shfl_xor(s,m);
  if(ln==0) vs[bh*80+d]=s;
}

// ---------------- fused k-features + ctx partial GEMM (deferred max) ----------------
__global__ __launch_bounds__(256) void kctx(const u16* __restrict__ kb, const u16* __restrict__ pj,
                                            const u16* __restrict__ vt,
                                            float* __restrict__ part, float* __restrict__ maxb){
  __shared__ u16 kl[64*64];     // [token][d], granule-swizzled by token&7
  __shared__ u16 vl[80*64];     // [d][n],     granule-swizzled by d&7
  __shared__ u16 kp_l[128*64];  // [m_local][n], granule-swizzled by m&7 (per-wave rows)
  __shared__ float dgl[64];
  const int kc=blockIdx.x, half=blockIdx.y, bh=blockIdx.z, b_=bh>>3, h_=bh&7;
  const int tid=threadIdx.x, wv=tid>>6, ln=tid&63;
  short8 pjf[2][2];
  #pragma unroll
  for(int i=0;i<2;i++)
    #pragma unroll
    for(int t=0;t<2;t++)
      pjf[i][t]=*(const short8*)&pj[(size_t)(half*128+wv*32+i*16+(ln&15))*DHEAD + t*32 + (ln>>4)*8];
  f32x4 ctx[2][5]={};
  float m_run=-3.0e38f;
  const u16* vbh=vt+(size_t)bh*VROWS*SEQ;
  for(int s=0;s<8;s++){
    const int n0s=kc*512+s*64;
    const u16* kg=kb+((size_t)(b_*SEQ+n0s))*DIMX + h_*DHEAD;
    #pragma unroll
    for(int cc=0;cc<2;cc++){
      int c=cc*256+wv*64+ln; int t=c>>3, g=c&7;
      gload16(kg+(size_t)t*DIMX+((g^(t&7))*8), &kl[(size_t)(cc*256+wv*64)*8]);
    }
    #pragma unroll
    for(int cc=0;cc<2;cc++){
      int c=cc*256+wv*64+ln; int d=c>>3, g=c&7;
      gload16(vbh+(size_t)d*SEQ+n0s+((g^(d&7))*8), &vl[(size_t)(cc*256+wv*64)*8]);
    }
    if(wv<2){
      int c=512+wv*64+ln; int d=c>>3, g=c&7;
      gload16(vbh+(size_t)d*SEQ+n0s+((g^(d&7))*8), &vl[(size_t)(512+wv*64)*8]);
    }
    __syncthreads();
    if(tid<64){
      float ss=0;
      #pragma unroll
      for(int gg=0;gg<8;gg++){
        short8 kv=*(const short8*)&kl[tid*64 + ((gg+tid)&7)*8];
        #pragma unroll
        for(int e=0;e<8;e++){ float x=bf2f((u16)kv[e]); ss+=x*x; }
      }
      dgl[tid]=ss*0.0625f; // 0.5 * d^-0.5
    }
    __syncthreads();
    f32x4 dd[2][4]={};
    #pragma unroll
    for(int tk=0;tk<2;tk++)
      #pragma unroll
      for(int j=0;j<4;j++){
        short8 bk_=*(const short8*)&kl[(j*16+(ln&15))*64 + (((tk*4+(ln>>4))^(ln&7))<<3)];
        #pragma unroll
        for(int i=0;i<2;i++)
          dd[i][j]=__builtin_amdgcn_mfma_f32_16x16x32_bf16(pjf[i][tk],bk_,dd[i][j],0,0,0);
      }
    float mt=-3.0e38f;
    #pragma unroll
    for(int i=0;i<2;i++)
      #pragma unroll
      for(int j=0;j<4;j++)
        #pragma unroll
        for(int r=0;r<4;r++) mt=fmaxf(mt,dd[i][j][r]);
    #pragma unroll
    for(int m=1;m<64;m<<=1) mt=fmaxf(mt,__shfl_xor(mt,m));
    if(mt>m_run){
      float sc=__expf(m_run-mt);
      #pragma unroll
      for(int i=0;i<2;i++)
        #pragma unroll
        for(int j2=0;j2<5;j2++) ctx[i][j2]*=sc;
      m_run=mt;
    }
    #pragma unroll
    for(int j=0;j<4;j++){
      const float dgn=dgl[j*16+(ln&15)];
      #pragma unroll
      for(int i=0;i<2;i++)
        #pragma unroll
        for(int r=0;r<4;r++){
          int m_l=wv*32+i*16+(ln>>4)*4+r;
          float E=__expf(dd[i][j][r]-dgn-m_run);
          kp_l[m_l*64 + (((j*2+((ln>>3)&1))^(m_l&7))<<3) + (ln&7)]=f2bf(E);
        }
    }
    #pragma unroll
    for(int tk=0;tk<2;tk++){
      short8 af2[2];
      #pragma unroll
      for(int i=0;i<2;i++)
        af2[i]=*(const short8*)&kp_l[(wv*32+i*16+(ln&15))*64 + (((tk*4+(ln>>4))^(ln&7))<<3)];
      #pragma unroll
      for(int j2=0;j2<5;j2++){
        short8 bf2=*(const short8*)&vl[(j2*16+(ln&15))*64 + (((tk*4+(ln>>4))^(ln&7))<<3)];
        #pragma unroll
        for(int i=0;i<2;i++)
          ctx[i][j2]=__builtin_amdgcn_mfma_f32_16x16x32_bf16(af2[i],bf2,ctx[i][j2],0,0,0);
      }
    }
    __syncthreads();
  }
  float* po=part + ((size_t)(bh*NCHUNK+kc))*(256*80) + (size_t)half*128*80;
  #pragma unroll
  for(int i=0;i<2;i++)
    #pragma unroll
    for(int j2=0;j2<5;j2++)
      #pragma unroll
      for(int r=0;r<4;r++)
        po[(size_t)(wv*32+i*16+(ln>>4)*4+r)*80 + j2*16+(ln&15)]=ctx[i][j2][r];
  if(ln==0) maxb[bh*128 + kc*8 + half*4 + wv]=m_run;
}

// ---------------- ctx reduce: rescale chunk partials + analytic eps ----------------
__global__ __launch_bounds__(256) void ctx_reduce(const float* __restrict__ part, const float* __restrict__ maxb,
                                                  const float* __restrict__ vs,
                                                  u16* __restrict__ ctxT, float* __restrict__ ksum){
  __shared__ float mx_s[128];
  __shared__ float sc_s[NCHUNK];
  const int mseg=blockIdx.x, bh=blockIdx.y, tid=threadIdx.x;
  if(tid<128) mx_s[tid]=maxb[(size_t)bh*128+tid];
  __syncthreads();
  float km=-3.0e38f;
  for(int i=0;i<128;i++) km=fmaxf(km,mx_s[i]);
  const int m0=mseg*32;
  const int half=m0>>7, wvv=(m0&127)>>5;
  if(tid<NCHUNK) sc_s[tid]=__expf(mx_s[tid*8+half*4+wvv]-km);
  __syncthreads();
  for(int rep=0;rep<10;rep++){
    int idx=rep*256+tid;           // 0..2559 = 32*80
    int mo=idx/80, d=idx-mo*80;
    int m=m0+mo;
    float s=0;
    #pragma unroll
    for(int c=0;c<NCHUNK;c++)
      s+=sc_s[c]*part[((size_t)(bh*NCHUNK+c))*(256*80) + (size_t)m*80 + d];
    float vsd=(d<=64)? vs[bh*80+d] : 0.0f;
    float val=0.0625f*(s + 1e-4f*vsd);
    if(d<64)       ctxT[((size_t)bh*64+d)*NBFX + m]=f2bf(val);
    else if(d==64) ksum[bh*NBFX+m]=val;
  }
}

// ---------------- column sums of ctxT / ksum ----------------
__global__ void csum_k(const u16* __restrict__ ctxT, const float* __restrict__ ksum, float* __restrict__ cs){
  const int bh=blockIdx.x, t=threadIdx.x;
  if(t<64){
    const u16* r=ctxT+((size_t)bh*64+t)*NBFX;
    float s=0;
    for(int m=0;m<NBFX;m+=8){
      short8 v=*(const short8*)&r[m];
      #pragma unroll
      for(int e=0;e<8;e++) s+=bf2f((u16)v[e]);
    }
    cs[bh*80+t]=s;
  } else if(t==64){
    float s=0;
    for(int m=0;m<NBFX;m++) s+=ksum[bh*NBFX+m];
    cs[bh*80+64]=s;
  }
}

// ---------------- fused query path (no-max E-form) ----------------
__global__ __launch_bounds__(256) void q_fused(const u16* __restrict__ qb, const u16* __restrict__ pj,
                                               const u16* __restrict__ ctxT, const float* __restrict__ ksum,
                                               const float* __restrict__ cs, u16* __restrict__ ob){
  __shared__ u16 ql[64*64];
  __shared__ u16 qpl[64*136];
  __shared__ float dgs[64];
  __shared__ float mred[4*64], dred[4*64];
  __shared__ float ff_s[64], dinv_s[64];
  const int bh=blockIdx.y, b_=bh>>3, h_=bh&7;
  const int n0=blockIdx.x*64;
  const int tid=threadIdx.x, wv=tid>>6, ln=tid&63;
  const u16* qg=qb+((size_t)(b_*SEQ+n0))*DIMX + h_*DHEAD;
  #pragma unroll
  for(int cc=0;cc<2;cc++){
    int c=cc*256+wv*64+ln; int t=c>>3, g=c&7;
    gload16(qg+(size_t)t*DIMX+((g^(t&7))*8), &ql[(size_t)(cc*256+wv*64)*8]);
  }
  short8 pjf[2][2][2];
  float ks[2][2][4];
  #pragma unroll
  for(int h=0;h<2;h++)
    #pragma unroll
    for(int i=0;i<2;i++){
      #pragma unroll
      for(int t=0;t<2;t++)
        pjf[h][i][t]=*(const short8*)&pj[(size_t)(h*128+wv*32+i*16+(ln&15))*DHEAD + t*32 + (ln>>4)*8];
      #pragma unroll
      for(int r=0;r<4;r++)
        ks[h][i][r]=ksum[bh*NBFX + h*128+wv*32+i*16+(ln>>4)*4+r];
    }
  const float KS=cs[bh*80+64];
  __syncthreads();
  if(tid<64){
    float ss=0;
    #pragma unroll
    for(int gg=0;gg<8;gg++){
      short8 kv=*(const short8*)&ql[tid*64 + ((gg+tid)&7)*8];
      #pragma unroll
      for(int e=0;e<8;e++){ float x=bf2f((u16)kv[e]); ss+=x*x; }
    }
    dgs[tid]=ss*0.0625f;
  }
  __syncthreads();
  float mxp[4]={-3.0e38f,-3.0e38f,-3.0e38f,-3.0e38f};
  float dnp[4]={0,0,0,0};
  f32x4 oc[4]={};
  const u16* cb=ctxT+(size_t)bh*64*NBFX;
  #pragma unroll
  for(int h=0;h<2;h++){
    #pragma unroll
    for(int j=0;j<4;j++){
      f32x4 dq[2]={};
      #pragma unroll
      for(int tk=0;tk<2;tk++){
        short8 bq=*(const short8*)&ql[(j*16+(ln&15))*64 + (((tk*4+(ln>>4))^(ln&7))<<3)];
        #pragma unroll
        for(int i=0;i<2;i++)
          dq[i]=__builtin_amdgcn_mfma_f32_16x16x32_bf16(pjf[h][i][tk],bq,dq[i],0,0,0);
      }
      const float dgn=dgs[j*16+(ln&15)];
      #pragma unroll
      for(int i=0;i<2;i++)
        #pragma unroll
        for(int r=0;r<4;r++){
          float d_=dq[i][r];
          mxp[j]=fmaxf(mxp[j],d_);
          float E=__expf(d_-dgn);
          dnp[j]+=E*ks[h][i][r];
          qpl[(j*16+(ln&15))*136 + wv*32+i*16+(ln>>4)*4+r]=f2bf(E);
        }
    }
    __syncthreads();
    #pragma unroll
    for(int mk2=0;mk2<4;mk2++){
      short8 aq=*(const short8*)&cb[(size_t)(wv*16+(ln&15))*NBFX + h*128 + mk2*32 + (ln>>4)*8];
      #pragma unroll
      for(int j2=0;j2<4;j2++){
        short8 bqp=*(const short8*)&qpl[(j2*16+(ln&15))*136 + mk2*32 + (ln>>4)*8];
        oc[j2]=__builtin_amdgcn_mfma_f32_16x16x32_bf16(aq,bqp,oc[j2],0,0,0);
      }
    }
    __syncthreads();
  }
  #pragma unroll
  for(int j=0;j<4;j++){
    #pragma unroll
    for(int msk=16;msk<64;msk<<=1){
      mxp[j]=fmaxf(mxp[j],__shfl_xor(mxp[j],msk));
      dnp[j]+=__shfl_xor(dnp[j],msk);
    }
  }
  if(ln<16){
    #pragma unroll
    for(int j=0;j<4;j++){ mred[wv*64+j*16+ln]=mxp[j]; dred[wv*64+j*16+ln]=dnp[j]; }
  }
  __syncthreads();
  if(tid<64){
    float mx=fmaxf(fmaxf(mred[tid],mred[64+tid]),fmaxf(mred[128+tid],mred[192+tid]));
    float dn=dred[tid]+dred[64+tid]+dred[128+tid]+dred[192+tid];
    float f=1e-4f*__expf(mx);
    ff_s[tid]=f;
    dinv_s[tid]=1.0f/(dn + f*KS);
  }
  __syncthreads();
  float csr[4];
  #pragma unroll
  for(int r=0;r<4;r++) csr[r]=cs[bh*80 + wv*16+(ln>>4)*4+r];
  u16* og=ob+((size_t)(b_*SEQ+n0))*DIMX + h_*DHEAD;
  #pragma unroll
  for(int j2=0;j2<4;j2++){
    int n=j2*16+(ln&15);
    float f=ff_s[n], di=dinv_s[n];
    u16 pk[4];
    #pragma unroll
    for(int r=0;r<4;r++) pk[r]=f2bf((oc[j2][r]+f*csr[r])*di);
    uint2 pv; pv.x=(unsigned)pk[0]|((unsigned)pk[1]<<16); pv.y=(unsigned)pk[2]|((unsigned)pk[3]<<16);
    *(uint2*)&og[(size_t)n*DIMX + wv*16+(ln>>4)*4]=pv;
  }
}

// ---------------- workspace layout (~190 MiB) ----------------
static constexpr size_t SZ_ACT=(size_t)TOK*DIMX*2;                 // 32 MiB
static constexpr size_t O_Y=0, O_Q=SZ_ACT, O_K=2*SZ_ACT;
static constexpr size_t O_VT=3*SZ_ACT;                             // 96 MiB
static constexpr size_t SZ_VT=(size_t)NBH*VROWS*SEQ*2;             // 40 MiB
static constexpr size_t O_PART=O_VT+SZ_VT;                         // 136 MiB
static constexpr size_t SZ_PART=(size_t)NBH*NCHUNK*256*80*4;       // 40 MiB
static constexpr size_t O_CTXT=O_PART+SZ_PART;                     // 176 MiB
static constexpr size_t SZ_CTXT=(size_t)NBH*64*NBFX*2;
static constexpr size_t O_KSUM=O_CTXT+SZ_CTXT;
static constexpr size_t SZ_KSUM=(size_t)NBH*NBFX*4;
static constexpr size_t O_MAX=O_KSUM+SZ_KSUM;
static constexpr size_t SZ_MAX=(size_t)NBH*128*4;
static constexpr size_t O_VSUM=O_MAX+SZ_MAX;
static constexpr size_t SZ_VSUM=(size_t)NBH*80*4;
static constexpr size_t O_CS=O_VSUM+SZ_VSUM;
static constexpr size_t SZ_CS=(size_t)NBH*80*4;
static constexpr size_t O_WQKV=O_CS+SZ_CS;
static constexpr size_t SZ_WQKV=(size_t)2*1536*DIMX*2;             // 3 MiB
static constexpr size_t O_WOT=O_WQKV+SZ_WQKV;
static constexpr size_t SZ_W=(size_t)2*DIMX*DIMX*2;                // 1 MiB
static constexpr size_t O_W1T=O_WOT+SZ_W;
static constexpr size_t SZ_W1=(size_t)2*FFD*DIMX*2;                // 4 MiB
static constexpr size_t O_W2T=O_W1T+SZ_W1;
static constexpr size_t O_PJ=O_W2T+SZ_W1;
static constexpr size_t O_QKVB=O_PJ+(size_t)2*NBFX*DHEAD*2;
static constexpr size_t WS_END=O_QKVB+(size_t)2*1536*4;

extern "C" void kernel_launch(void* const* d_in, const int* in_sizes, int n_in,
                              void* d_out, int out_size, void* d_ws, size_t ws_size,
                              hipStream_t stream){
  (void)in_sizes;(void)n_in;(void)out_size;
  const float* xin =(const float*)d_in[0];
  const float* ln1g=(const float*)d_in[1];
  const float* ln1b=(const float*)d_in[2];
  const float* ln2g=(const float*)d_in[3];
  const float* ln2b=(const float*)d_in[4];
  const float* Wq=(const float*)d_in[5];
  const float* bq=(const float*)d_in[6];
  const float* Wk=(const float*)d_in[7];
  const float* bk=(const float*)d_in[8];
  const float* Wv=(const float*)d_in[9];
  const float* bv=(const float*)d_in[10];
  const float* Wo=(const float*)d_in[11];
  const float* bo=(const float*)d_in[12];
  const float* proj=(const float*)d_in[13];
  const float* W1=(const float*)d_in[14];
  const float* b1=(const float*)d_in[15];
  const float* W2=(const float*)d_in[16];
  const float* b2=(const float*)d_in[17];
  float* xout=(float*)d_out;

  copy_f32<<<(TOK*DIMX/4)/256,256,0,stream>>>((const float4*)xin,(float4*)xout, TOK*DIMX/4);
  if(ws_size < WS_END) return;

  char* ws=(char*)d_ws;
  u16* ybuf =(u16*)(ws+O_Y);
  u16* qbuf =(u16*)(ws+O_Q);
  u16* kbuf =(u16*)(ws+O_K);
  u16* vtb  =(u16*)(ws+O_VT);
  float* partb=(float*)(ws+O_PART);
  u16* ctxtb=(u16*)(ws+O_CTXT);
  float* ksumb=(float*)(ws+O_KSUM);
  float* maxb=(float*)(ws+O_MAX);
  float* vsumb=(float*)(ws+O_VSUM);
  float* csb=(float*)(ws+O_CS);
  u16* wqkvt=(u16*)(ws+O_WQKV);
  u16* wot=(u16*)(ws+O_WOT);
  u16* w1t=(u16*)(ws+O_W1T); u16* w2t=(u16*)(ws+O_W2T);
  u16* pjb=(u16*)(ws+O_PJ);
  float* qkvb=(float*)(ws+O_QKVB);
  u16* hbuf=(u16*)(ws+O_Q);   // FF hidden [32768][2048] reuses q/k/vt/part regions

  for(int l=0;l<2;l++){
    size_t wo=(size_t)l*DIMX*DIMX;
    convT<<<dim3(16,16),dim3(32,8),0,stream>>>(Wq+wo, wqkvt+(size_t)(l*1536+   0)*DIMX, DIMX, DIMX);
    convT<<<dim3(16,16),dim3(32,8),0,stream>>>(Wk+wo, wqkvt+(size_t)(l*1536+ 512)*DIMX, DIMX, DIMX);
    convT<<<dim3(16,16),dim3(32,8),0,stream>>>(Wv+wo, wqkvt+(size_t)(l*1536+1024)*DIMX, DIMX, DIMX);
    convT<<<dim3(16,16),dim3(32,8),0,stream>>>(Wo+wo, wot+wo, DIMX, DIMX);
    size_t w1o=(size_t)l*DIMX*FFD;
    convT<<<dim3(64,16),dim3(32,8),0,stream>>>(W1+w1o, w1t+w1o, DIMX, FFD);
    convT<<<dim3(16,64),dim3(32,8),0,stream>>>(W2+w1o, w2t+w1o, FFD, DIMX);
  }
  conv_proj<<<(2*NBFX*DHEAD)/256,256,0,stream>>>(proj, pjb, 2*NBFX*DHEAD);
  pack_bias<<<12,256,0,stream>>>(bq,bk,bv,qkvb);

  for(int l=0;l<2;l++){
    const u16* wqkvt_l=wqkvt+(size_t)l*1536*DIMX;
    const u16* wot_l=wot+(size_t)l*DIMX*DIMX;
    const u16* w1t_l=w1t+(size_t)l*DIMX*FFD;
    const u16* w2t_l=w2t+(size_t)l*DIMX*FFD;
    const u16* pj_l =pjb+(size_t)l*NBFX*DHEAD;
    const float* qkvb_l=qkvb+(size_t)l*1536;

    ln_k<<<TOK/4,256,0,stream>>>(xout, ln1g+l*DIMX, ln1b+l*DIMX, ybuf);
    fill_vt<<<(NBH*16*SEQ)/256,256,0,stream>>>(vtb);
    gemm256<0><<<dim3(6,128),512,0,stream>>>(ybuf, wqkvt_l, qkvb_l, qbuf, vtb, TOK, 1536, DIMX);
    vsum_k<<<520,256,0,stream>>>(vtb, vsumb);
    kctx<<<dim3(NCHUNK,2,32),256,0,stream>>>(kbuf, pj_l, vtb, partb, maxb);
    ctx_reduce<<<dim3(8,32),256,0,stream>>>(partb, maxb, vsumb, ctxtb, ksumb);
    csum_k<<<32,256,0,stream>>>(ctxtb, ksumb, csb);
    q_fused<<<dim3(128,32),256,0,stream>>>(qbuf, pj_l, ctxtb, ksumb, csb, ybuf);
    gemm256<1><<<dim3(2,128),512,0,stream>>>(ybuf, wot_l, bo+l*DIMX, xout, nullptr, TOK, DIMX, DIMX);
    ln_k<<<TOK/4,256,0,stream>>>(xout, ln2g+l*DIMX, ln2b+l*DIMX, ybuf);
    gemm256<2><<<dim3(8,128),512,0,stream>>>(ybuf, w1t_l, b1+l*FFD, hbuf, nullptr, TOK, FFD, DIMX);
    gemm256<1><<<dim3(2,128),512,0,stream>>>(hbuf, w2t_l, b2+l*DIMX, xout, nullptr, TOK, DIMX, FFD);
  }
}

// Round 6
// 1046.871 us; speedup vs baseline: 1.5892x; 1.0073x over previous
//
#include <hip/hip_runtime.h>
#include <math.h>

#define DIMX 512
#define HEADS 8
#define DHEAD 64
#define NBFX 256
#define FFD 2048
#define NBX 4
#define SEQ 8192
#define TOK (NBX*SEQ)     // 32768 tokens
#define NBH (NBX*HEADS)   // 32 (b,h) pairs
#define VROWS 80          // 64 v-dims + ones row(64) + zeros pad
#define NCHUNK 16         // ctx K-split chunks (512 tokens each)
#define BK 64

typedef unsigned short u16;
typedef __attribute__((ext_vector_type(8))) short short8;
typedef __attribute__((ext_vector_type(4))) float f32x4;

__device__ __forceinline__ float bf2f(u16 x){ return __uint_as_float(((unsigned)x)<<16); }
__device__ __forceinline__ u16 f2bf(float f){
  unsigned u=__float_as_uint(f);
  return (u16)((u + 0x7FFFu + ((u>>16)&1u))>>16);
}
__device__ __forceinline__ void gload16(const void* g, void* l){
  __builtin_amdgcn_global_load_lds((const __attribute__((address_space(1))) void*)g,
                                   (__attribute__((address_space(3))) void*)l, 16, 0, 0);
}
// exact-GELU via A&S 7.1.26 erf approx (max erf err 1.5e-7)
__device__ __forceinline__ float gelu_f(float v){
  float x=v*0.70710678118654752f;
  float ax=fabsf(x);
  float t=1.0f/(1.0f+0.3275911f*ax);
  float p=t*(0.254829592f+t*(-0.284496736f+t*(1.421413741f+t*(-1.453152027f+t*1.061405429f))));
  float erfv=1.0f-p*__expf(-ax*ax);
  erfv=(x<0.0f)? -erfv : erfv;
  return 0.5f*v*(1.0f+erfv);
}

#define FENCE asm volatile(""::: "memory")
#define BAR() do{ __builtin_amdgcn_sched_barrier(0); FENCE; __builtin_amdgcn_s_barrier(); FENCE; __builtin_amdgcn_sched_barrier(0);}while(0)

// ---------------- prep / elementwise ----------------
__global__ void copy_f32(const float4* __restrict__ s, float4* __restrict__ d, int n4){
  int i=blockIdx.x*blockDim.x+threadIdx.x;
  if(i<n4) d[i]=s[i];
}
__global__ void conv_proj(const float* __restrict__ p, u16* __restrict__ o, int n){
  int i=blockIdx.x*blockDim.x+threadIdx.x;
  if(i<n) o[i]=f2bf(p[i]*0.35355339059327373f); // fold d^-0.25 into proj
}
// src fp32 [K][Ncol] -> dst bf16 [Ncol][K] (transposed)
__global__ void convT(const float* __restrict__ src, u16* __restrict__ dst, int K, int Ncol){
  __shared__ float t[32][33];
  int k0=blockIdx.y*32, n0=blockIdx.x*32;
  int tx=threadIdx.x, ty=threadIdx.y;
  for(int i=ty;i<32;i+=8) t[i][tx]=src[(size_t)(k0+i)*Ncol + n0+tx];
  __syncthreads();
  for(int i=ty;i<32;i+=8) dst[(size_t)(n0+i)*K + k0+tx]=f2bf(t[tx][i]);
}
__global__ void fill_vt(u16* __restrict__ vt){
  int i=blockIdx.x*blockDim.x+threadIdx.x; // < NBH*16*SEQ = 2^22
  int n=i&(SEQ-1); int r=(i>>13)&15; int bh=i>>17;
  vt[((size_t)bh*VROWS + 64 + r)*SEQ + n] = (r==0)? (u16)0x3F80 : (u16)0;
}
__global__ void pack_bias(const float* __restrict__ bq, const float* __restrict__ bk,
                          const float* __restrict__ bv, float* __restrict__ o){
  int i=blockIdx.x*blockDim.x+threadIdx.x; // 2*1536
  int l=i/1536, c=i-l*1536;
  const float* s=(c<512)? bq : ((c<1024)? bk : bv);
  o[i]=s[l*512 + (c&511)];
}

// wave-per-row LN: 4 rows/block, no LDS/barriers
__global__ __launch_bounds__(256) void ln_k(const float* __restrict__ x, const float* __restrict__ g,
                                            const float* __restrict__ b, u16* __restrict__ y){
  const int row=blockIdx.x*4 + (threadIdx.x>>6);
  const int ln=threadIdx.x&63;
  const float* xr=x+(size_t)row*DIMX;
  float4 v0=*(const float4*)&xr[ln*8];
  float4 v1=*(const float4*)&xr[ln*8+4];
  float v[8]={v0.x,v0.y,v0.z,v0.w,v1.x,v1.y,v1.z,v1.w};
  float s=0;
  #pragma unroll
  for(int e=0;e<8;e++) s+=v[e];
  #pragma unroll
  for(int m=1;m<64;m<<=1) s+=__shfl_xor(s,m);
  const float mean=s*(1.0f/DIMX);
  float s2=0;
  #pragma unroll
  for(int e=0;e<8;e++){ v[e]-=mean; s2+=v[e]*v[e]; }
  #pragma unroll
  for(int m=1;m<64;m<<=1) s2+=__shfl_xor(s2,m);
  const float rs=rsqrtf(s2*(1.0f/DIMX)+1e-5f);
  u16* yr=y+(size_t)row*DIMX+ln*8;
  u16 pk[8];
  #pragma unroll
  for(int e=0;e<8;e++) pk[e]=f2bf(v[e]*rs*g[ln*8+e]+b[ln*8+e]);
  uint4 pv;
  pv.x=(unsigned)pk[0]|((unsigned)pk[1]<<16); pv.y=(unsigned)pk[2]|((unsigned)pk[3]<<16);
  pv.z=(unsigned)pk[4]|((unsigned)pk[5]<<16); pv.w=(unsigned)pk[6]|((unsigned)pk[7]<<16);
  *(uint4*)yr=pv;
}

// ---------------- 256x256 8-phase pipelined bf16 GEMM (static addressing) ----------------
// C = A[M,K] * Bt[N,K]^T + bias.  EPI 0: QKV (q/k bf16 + vT); 1: fp32 +=; 2: gelu->bf16
#define MFMA16(MH,BF,NH) do{                                                             \
  __builtin_amdgcn_s_setprio(1);                                                         \
  _Pragma("unroll") for(int kk_=0;kk_<2;kk_++)                                           \
    _Pragma("unroll") for(int i_=0;i_<4;i_++)                                            \
      _Pragma("unroll") for(int j_=0;j_<2;j_++)                                          \
        acc[MH][i_][NH][j_]=__builtin_amdgcn_mfma_f32_16x16x32_bf16(af[i_][kk_],BF[j_][kk_],acc[MH][i_][NH][j_],0,0,0); \
  __builtin_amdgcn_s_setprio(0);                                                         \
}while(0)

// stage half-tile (2 gloads) of tile T into buffer BUF (compile-time BUF/HALF/ISB)
#define STG(T,HALF,ISB,BUF) do{ if((T)<nt){                                              \
  gload16(gp[ISB][HALF][0]+(size_t)(T)*BK, &lds[BUF][ISB][(HALF)*128 +    wv*8][0]);     \
  gload16(gp[ISB][HALF][1]+(size_t)(T)*BK, &lds[BUF][ISB][(HALF)*128 + 64+wv*8][0]); } }while(0)

#define LDA(BUF,MH) do{                                                                  \
  _Pragma("unroll") for(int i_=0;i_<4;i_++)                                              \
    _Pragma("unroll") for(int kk_=0;kk_<2;kk_++)                                         \
      af[i_][kk_]=*(const short8*)((const u16*)lds[BUF][0] + aoffs[MH][i_][kk_]); }while(0)

#define LDB(BF,BUF,NH) do{                                                               \
  _Pragma("unroll") for(int j_=0;j_<2;j_++)                                              \
    _Pragma("unroll") for(int kk_=0;kk_<2;kk_++)                                         \
      BF[j_][kk_]=*(const short8*)((const u16*)lds[BUF][1] + boffs[NH][j_][kk_]); }while(0)

#define TILE(T,BUF,OBUF) do{                                                             \
  LDB(bf0,BUF,0); LDA(BUF,0);                                                            \
  STG((T)+1,1,0,OBUF);                                                                   \
  BAR(); MFMA16(0,bf0,0); BAR();                                                         \
  LDB(bf1,BUF,1);                                                                        \
  STG((T)+1,1,1,OBUF);                                                                   \
  BAR(); MFMA16(0,bf1,1); BAR();                                                         \
  LDA(BUF,1);                                                                            \
  STG((T)+2,0,1,BUF);                                                                    \
  BAR(); MFMA16(1,bf0,0); BAR();                                                         \
  STG((T)+2,0,0,BUF);                                                                    \
  BAR(); MFMA16(1,bf1,1);                                                                \
  if((T)+2<nt) asm volatile("s_waitcnt vmcnt(4)":::"memory");                            \
  else         asm volatile("s_waitcnt vmcnt(0)":::"memory");                            \
  BAR();                                                                                 \
}while(0)

template<int EPI,int K>
__global__ __launch_bounds__(512,2) void gemm256(const u16* __restrict__ A, const u16* __restrict__ Bt,
                                                 const float* __restrict__ bias, void* __restrict__ outp,
                                                 u16* __restrict__ out2, int Ncol){
  constexpr int nt=K/BK;
  __shared__ u16 lds[2][2][256][64];   // [buf][A=0/B=1][row][col(swizzled granules)]
  const int tid=threadIdx.x, wv=tid>>6, ln=tid&63;
  const int wr=wv>>2, wc=wv&3;          // 2 x 4 wave grid
  // XCD-band swizzle: all x-blocks of an A-panel band -> same XCD (requires gy%8==0)
  const int gx=gridDim.x, gy=gridDim.y;
  const int P=blockIdx.y*gx+blockIdx.x;
  const int band=gy>>3;
  const int xcd=P&7, sI=P>>3;
  const int by=xcd*band + (sI - (sI/band)*band);
  const int bx=sI/band;
  const int m0=by*256, n0=bx*256;
  f32x4 acc[2][4][2][2]={};             // [mh][i][nh][j]

  // hoisted global stage pointers [isB][half][s]
  const u16* gp[2][2][2];
  #pragma unroll
  for(int isB=0;isB<2;isB++)
    #pragma unroll
    for(int half=0;half<2;half++)
      #pragma unroll
      for(int s=0;s<2;s++){
        int G=s*512+wv*64+ln;
        int arow=half*128+(G>>3), g=G&7;
        const u16* src=isB? Bt:A;
        int b0=isB? n0:m0;
        gp[isB][half][s]=src+(size_t)(b0+arow)*K+((g^(arow&7))<<3);
      }
  // hoisted LDS fragment element-offsets (within one [256][64] array)
  int aoffs[2][4][2], boffs[2][2][2];
  #pragma unroll
  for(int mh=0;mh<2;mh++)
    #pragma unroll
    for(int i=0;i<4;i++){
      int row=wr*128+mh*64+i*16+(ln&15);
      #pragma unroll
      for(int kk=0;kk<2;kk++)
        aoffs[mh][i][kk]=row*64+((((kk*4+(ln>>4)))^(row&7))<<3);
    }
  #pragma unroll
  for(int nh=0;nh<2;nh++)
    #pragma unroll
    for(int j=0;j<2;j++){
      int row=wc*64+nh*32+j*16+(ln&15);
      #pragma unroll
      for(int kk=0;kk<2;kk++)
        boffs[nh][j][kk]=row*64+((((kk*4+(ln>>4)))^(row&7))<<3);
    }

  short8 af[4][2], bf0[2][2], bf1[2][2];

  // prologue: tile0 fully + tile1's B0,A0
  STG(0,0,0,0); STG(0,1,0,0); STG(0,0,1,0); STG(0,1,1,0);
  STG(1,0,1,1); STG(1,0,0,1);
  asm volatile("s_waitcnt vmcnt(4)":::"memory");
  BAR();

  #pragma unroll 1
  for(int t=0;t<nt;t+=2){
    TILE(t,0,1);
    TILE(t+1,1,0);
  }

  // epilogue
  #pragma unroll
  for(int mh=0;mh<2;mh++)
  #pragma unroll
  for(int i=0;i<4;i++)
  #pragma unroll
  for(int nh=0;nh<2;nh++)
  #pragma unroll
  for(int j=0;j<2;j++){
    const int row=m0+wr*128+mh*64+i*16+(ln>>4)*4;
    const int col=n0+wc*64+nh*32+j*16+(ln&15);
    const float bv=bias[col];
    const f32x4 a=acc[mh][i][nh][j];
    if constexpr(EPI==0){
      if(col<1024){ // q (region 0) / k (region 1), row-major [TOK][512]
        u16* o=(u16*)outp + (size_t)(col>>9)*TOK*DIMX + (col&511);
        #pragma unroll
        for(int r=0;r<4;r++) o[(size_t)(row+r)*DIMX]=f2bf(a[r]+bv);
      } else {      // vT[b,h,d,n] transposed write, 4 tokens packed
        const int hd=col-1024, h_=hd>>6, d_=hd&63, b_=row>>13, nn=row&(SEQ-1);
        u16 pk[4];
        #pragma unroll
        for(int r=0;r<4;r++) pk[r]=f2bf(a[r]+bv);
        uint2 pv; pv.x=(unsigned)pk[0]|((unsigned)pk[1]<<16); pv.y=(unsigned)pk[2]|((unsigned)pk[3]<<16);
        *(uint2*)&out2[((size_t)(b_*HEADS+h_)*VROWS+d_)*SEQ+nn]=pv;
      }
    } else if constexpr(EPI==1){
      float* o=(float*)outp;
      #pragma unroll
      for(int r=0;r<4;r++){ size_t ix=(size_t)(row+r)*Ncol+col; o[ix]+=a[r]+bv; }
    } else {
      u16* o=(u16*)outp;
      #pragma unroll
      for(int r=0;r<4;r++)
        o[(size_t)(row+r)*Ncol+col]=f2bf(gelu_f(a[r]+bv));
    }
  }
}

// ---------------- vsum: per (bh,d<=64) row-sum of vT over all n ----------------
__global__ __launch_bounds__(256) void vsum_k(const u16* __restrict__ vt, float* __restrict__ vs){
  const int gw=blockIdx.x*4 + (threadIdx.x>>6); // 0..2079 = 32*65
  const int ln=threadIdx.x&63;
  const int bh=gw/65, d=gw-bh*65;
  const u16* row=vt+((size_t)bh*VROWS+d)*SEQ;
  float s=0;
  for(int it=0;it<16;it++){
    short8 v=*(const short8*)&row[it*512+ln*8];
    #pragma unroll
    for(int e=0;e<8;e++) s+=bf2f((u16)v[e]);
  }
  #pragma unroll
  for(int m=1;m<64;m<<=1) s+=__shfl_xor(s,m);
  if(ln==0) vs[bh*80+d]=s;
}

// ---------------- fused k-features + ctx partial GEMM (deferred max) ----------------
__global__ __launch_bounds__(256) void kctx(const u16* __restrict__ kb, const u16* __restrict__ pj,
                                            const u16* __restrict__ vt,
                                            float* __restrict__ part, float* __restrict__ maxb){
  __shared__ u16 kl[64*64];     // [token][d], granule-swizzled by token&7
  __shared__ u16 vl[80*64];     // [d][n],     granule-swizzled by d&7
  __shared__ u16 kp_l[128*64];  // [m_local][n], granule-swizzled by m&7 (per-wave rows)
  __shared__ float dgl[64];
  const int kc=blockIdx.x, half=blockIdx.y, bh=blockIdx.z, b_=bh>>3, h_=bh&7;
  const int tid=threadIdx.x, wv=tid>>6, ln=tid&63;
  short8 pjf[2][2];
  #pragma unroll
  for(int i=0;i<2;i++)
    #pragma unroll
    for(int t=0;t<2;t++)
      pjf[i][t]=*(const short8*)&pj[(size_t)(half*128+wv*32+i*16+(ln&15))*DHEAD + t*32 + (ln>>4)*8];
  f32x4 ctx[2][5]={};
  float m_run=-3.0e38f;
  const u16* vbh=vt+(size_t)bh*VROWS*SEQ;
  for(int s=0;s<8;s++){
    const int n0s=kc*512+s*64;
    const u16* kg=kb+((size_t)(b_*SEQ+n0s))*DIMX + h_*DHEAD;
    #pragma unroll
    for(int cc=0;cc<2;cc++){
      int c=cc*256+wv*64+ln; int t=c>>3, g=c&7;
      gload16(kg+(size_t)t*DIMX+((g^(t&7))*8), &kl[(size_t)(cc*256+wv*64)*8]);
    }
    #pragma unroll
    for(int cc=0;cc<2;cc++){
      int c=cc*256+wv*64+ln; int d=c>>3, g=c&7;
      gload16(vbh+(size_t)d*SEQ+n0s+((g^(d&7))*8), &vl[(size_t)(cc*256+wv*64)*8]);
    }
    if(wv<2){
      int c=512+wv*64+ln; int d=c>>3, g=c&7;
      gload16(vbh+(size_t)d*SEQ+n0s+((g^(d&7))*8), &vl[(size_t)(512+wv*64)*8]);
    }
    __syncthreads();
    if(tid<64){
      float ss=0;
      #pragma unroll
      for(int gg=0;gg<8;gg++){
        short8 kv=*(const short8*)&kl[tid*64 + ((gg+tid)&7)*8];
        #pragma unroll
        for(int e=0;e<8;e++){ float x=bf2f((u16)kv[e]); ss+=x*x; }
      }
      dgl[tid]=ss*0.0625f; // 0.5 * d^-0.5
    }
    __syncthreads();
    f32x4 dd[2][4]={};
    #pragma unroll
    for(int tk=0;tk<2;tk++)
      #pragma unroll
      for(int j=0;j<4;j++){
        short8 bk_=*(const short8*)&kl[(j*16+(ln&15))*64 + (((tk*4+(ln>>4))^(ln&7))<<3)];
        #pragma unroll
        for(int i=0;i<2;i++)
          dd[i][j]=__builtin_amdgcn_mfma_f32_16x16x32_bf16(pjf[i][tk],bk_,dd[i][j],0,0,0);
      }
    float mt=-3.0e38f;
    #pragma unroll
    for(int i=0;i<2;i++)
      #pragma unroll
      for(int j=0;j<4;j++)
        #pragma unroll
        for(int r=0;r<4;r++) mt=fmaxf(mt,dd[i][j][r]);
    #pragma unroll
    for(int m=1;m<64;m<<=1) mt=fmaxf(mt,__shfl_xor(mt,m));
    if(mt>m_run){
      float sc=__expf(m_run-mt);
      #pragma unroll
      for(int i=0;i<2;i++)
        #pragma unroll
        for(int j2=0;j2<5;j2++) ctx[i][j2]*=sc;
      m_run=mt;
    }
    #pragma unroll
    for(int j=0;j<4;j++){
      const float dgn=dgl[j*16+(ln&15)];
      #pragma unroll
      for(int i=0;i<2;i++)
        #pragma unroll
        for(int r=0;r<4;r++){
          int m_l=wv*32+i*16+(ln>>4)*4+r;
          float E=__expf(dd[i][j][r]-dgn-m_run);
          kp_l[m_l*64 + (((j*2+((ln>>3)&1))^(m_l&7))<<3) + (ln&7)]=f2bf(E);
        }
    }
    #pragma unroll
    for(int tk=0;tk<2;tk++){
      short8 af2[2];
      #pragma unroll
      for(int i=0;i<2;i++)
        af2[i]=*(const short8*)&kp_l[(wv*32+i*16+(ln&15))*64 + (((tk*4+(ln>>4))^(ln&7))<<3)];
      #pragma unroll
      for(int j2=0;j2<5;j2++){
        short8 bf2=*(const short8*)&vl[(j2*16+(ln&15))*64 + (((tk*4+(ln>>4))^(ln&7))<<3)];
        #pragma unroll
        for(int i=0;i<2;i++)
          ctx[i][j2]=__builtin_amdgcn_mfma_f32_16x16x32_bf16(af2[i],bf2,ctx[i][j2],0,0,0);
      }
    }
    __syncthreads();
  }
  float* po=part + ((size_t)(bh*NCHUNK+kc))*(256*80) + (size_t)half*128*80;
  #pragma unroll
  for(int i=0;i<2;i++)
    #pragma unroll
    for(int j2=0;j2<5;j2++)
      #pragma unroll
      for(int r=0;r<4;r++)
        po[(size_t)(wv*32+i*16+(ln>>4)*4+r)*80 + j2*16+(ln&15)]=ctx[i][j2][r];
  if(ln==0) maxb[bh*128 + kc*8 + half*4 + wv]=m_run;
}

// ---------------- ctx reduce: rescale chunk partials + analytic eps ----------------
__global__ __launch_bounds__(256) void ctx_reduce(const float* __restrict__ part, const float* __restrict__ maxb,
                                                  const float* __restrict__ vs,
                                                  u16* __restrict__ ctxT, float* __restrict__ ksum){
  __shared__ float mx_s[128];
  __shared__ float sc_s[NCHUNK];
  const int mseg=blockIdx.x, bh=blockIdx.y, tid=threadIdx.x;
  if(tid<128) mx_s[tid]=maxb[(size_t)bh*128+tid];
  __syncthreads();
  float km=-3.0e38f;
  for(int i=0;i<128;i++) km=fmaxf(km,mx_s[i]);
  const int m0=mseg*32;
  const int half=m0>>7, wvv=(m0&127)>>5;
  if(tid<NCHUNK) sc_s[tid]=__expf(mx_s[tid*8+half*4+wvv]-km);
  __syncthreads();
  for(int rep=0;rep<10;rep++){
    int idx=rep*256+tid;           // 0..2559 = 32*80
    int mo=idx/80, d=idx-mo*80;
    int m=m0+mo;
    float s=0;
    #pragma unroll
    for(int c=0;c<NCHUNK;c++)
      s+=sc_s[c]*part[((size_t)(bh*NCHUNK+c))*(256*80) + (size_t)m*80 + d];
    float vsd=(d<=64)? vs[bh*80+d] : 0.0f;
    float val=0.0625f*(s + 1e-4f*vsd);
    if(d<64)       ctxT[((size_t)bh*64+d)*NBFX + m]=f2bf(val);
    else if(d==64) ksum[bh*NBFX+m]=val;
  }
}

// ---------------- column sums of ctxT / ksum ----------------
__global__ void csum_k(const u16* __restrict__ ctxT, const float* __restrict__ ksum, float* __restrict__ cs){
  const int bh=blockIdx.x, t=threadIdx.x;
  if(t<64){
    const u16* r=ctxT+((size_t)bh*64+t)*NBFX;
    float s=0;
    for(int m=0;m<NBFX;m+=8){
      short8 v=*(const short8*)&r[m];
      #pragma unroll
      for(int e=0;e<8;e++) s+=bf2f((u16)v[e]);
    }
    cs[bh*80+t]=s;
  } else if(t==64){
    float s=0;
    for(int m=0;m<NBFX;m++) s+=ksum[bh*NBFX+m];
    cs[bh*80+64]=s;
  }
}

// ---------------- fused query path (no-max E-form) ----------------
__global__ __launch_bounds__(256) void q_fused(const u16* __restrict__ qb, const u16* __restrict__ pj,
                                               const u16* __restrict__ ctxT, const float* __restrict__ ksum,
                                               const float* __restrict__ cs, u16* __restrict__ ob){
  __shared__ u16 ql[64*64];
  __shared__ u16 qpl[64*136];
  __shared__ float dgs[64];
  __shared__ float mred[4*64], dred[4*64];
  __shared__ float ff_s[64], dinv_s[64];
  const int bh=blockIdx.y, b_=bh>>3, h_=bh&7;
  const int n0=blockIdx.x*64;
  const int tid=threadIdx.x, wv=tid>>6, ln=tid&63;
  const u16* qg=qb+((size_t)(b_*SEQ+n0))*DIMX + h_*DHEAD;
  #pragma unroll
  for(int cc=0;cc<2;cc++){
    int c=cc*256+wv*64+ln; int t=c>>3, g=c&7;
    gload16(qg+(size_t)t*DIMX+((g^(t&7))*8), &ql[(size_t)(cc*256+wv*64)*8]);
  }
  short8 pjf[2][2][2];
  float ks[2][2][4];
  #pragma unroll
  for(int h=0;h<2;h++)
    #pragma unroll
    for(int i=0;i<2;i++){
      #pragma unroll
      for(int t=0;t<2;t++)
        pjf[h][i][t]=*(const short8*)&pj[(size_t)(h*128+wv*32+i*16+(ln&15))*DHEAD + t*32 + (ln>>4)*8];
      #pragma unroll
      for(int r=0;r<4;r++)
        ks[h][i][r]=ksum[bh*NBFX + h*128+wv*32+i*16+(ln>>4)*4+r];
    }
  const float KS=cs[bh*80+64];
  __syncthreads();
  if(tid<64){
    float ss=0;
    #pragma unroll
    for(int gg=0;gg<8;gg++){
      short8 kv=*(const short8*)&ql[tid*64 + ((gg+tid)&7)*8];
      #pragma unroll
      for(int e=0;e<8;e++){ float x=bf2f((u16)kv[e]); ss+=x*x; }
    }
    dgs[tid]=ss*0.0625f;
  }
  __syncthreads();
  float mxp[4]={-3.0e38f,-3.0e38f,-3.0e38f,-3.0e38f};
  float dnp[4]={0,0,0,0};
  f32x4 oc[4]={};
  const u16* cb=ctxT+(size_t)bh*64*NBFX;
  #pragma unroll
  for(int h=0;h<2;h++){
    #pragma unroll
    for(int j=0;j<4;j++){
      f32x4 dq[2]={};
      #pragma unroll
      for(int tk=0;tk<2;tk++){
        short8 bq=*(const short8*)&ql[(j*16+(ln&15))*64 + (((tk*4+(ln>>4))^(ln&7))<<3)];
        #pragma unroll
        for(int i=0;i<2;i++)
          dq[i]=__builtin_amdgcn_mfma_f32_16x16x32_bf16(pjf[h][i][tk],bq,dq[i],0,0,0);
      }
      const float dgn=dgs[j*16+(ln&15)];
      #pragma unroll
      for(int i=0;i<2;i++)
        #pragma unroll
        for(int r=0;r<4;r++){
          float d_=dq[i][r];
          mxp[j]=fmaxf(mxp[j],d_);
          float E=__expf(d_-dgn);
          dnp[j]+=E*ks[h][i][r];
          qpl[(j*16+(ln&15))*136 + wv*32+i*16+(ln>>4)*4+r]=f2bf(E);
        }
    }
    __syncthreads();
    #pragma unroll
    for(int mk2=0;mk2<4;mk2++){
      short8 aq=*(const short8*)&cb[(size_t)(wv*16+(ln&15))*NBFX + h*128 + mk2*32 + (ln>>4)*8];
      #pragma unroll
      for(int j2=0;j2<4;j2++){
        short8 bqp=*(const short8*)&qpl[(j2*16+(ln&15))*136 + mk2*32 + (ln>>4)*8];
        oc[j2]=__builtin_amdgcn_mfma_f32_16x16x32_bf16(aq,bqp,oc[j2],0,0,0);
      }
    }
    __syncthreads();
  }
  #pragma unroll
  for(int j=0;j<4;j++){
    #pragma unroll
    for(int msk=16;msk<64;msk<<=1){
      mxp[j]=fmaxf(mxp[j],__shfl_xor(mxp[j],msk));
      dnp[j]+=__shfl_xor(dnp[j],msk);
    }
  }
  if(ln<16){
    #pragma unroll
    for(int j=0;j<4;j++){ mred[wv*64+j*16+ln]=mxp[j]; dred[wv*64+j*16+ln]=dnp[j]; }
  }
  __syncthreads();
  if(tid<64){
    float mx=fmaxf(fmaxf(mred[tid],mred[64+tid]),fmaxf(mred[128+tid],mred[192+tid]));
    float dn=dred[tid]+dred[64+tid]+dred[128+tid]+dred[192+tid];
    float f=1e-4f*__expf(mx);
    ff_s[tid]=f;
    dinv_s[tid]=1.0f/(dn + f*KS);
  }
  __syncthreads();
  float csr[4];
  #pragma unroll
  for(int r=0;r<4;r++) csr[r]=cs[bh*80 + wv*16+(ln>>4)*4+r];
  u16* og=ob+((size_t)(b_*SEQ+n0))*DIMX + h_*DHEAD;
  #pragma unroll
  for(int j2=0;j2<4;j2++){
    int n=j2*16+(ln&15);
    float f=ff_s[n], di=dinv_s[n];
    u16 pk[4];
    #pragma unroll
    for(int r=0;r<4;r++) pk[r]=f2bf((oc[j2][r]+f*csr[r])*di);
    uint2 pv; pv.x=(unsigned)pk[0]|((unsigned)pk[1]<<16); pv.y=(unsigned)pk[2]|((unsigned)pk[3]<<16);
    *(uint2*)&og[(size_t)n*DIMX + wv*16+(ln>>4)*4]=pv;
  }
}

// ---------------- workspace layout (~190 MiB) ----------------
static constexpr size_t SZ_ACT=(size_t)TOK*DIMX*2;                 // 32 MiB
static constexpr size_t O_Y=0, O_Q=SZ_ACT, O_K=2*SZ_ACT;
static constexpr size_t O_VT=3*SZ_ACT;                             // 96 MiB
static constexpr size_t SZ_VT=(size_t)NBH*VROWS*SEQ*2;             // 40 MiB
static constexpr size_t O_PART=O_VT+SZ_VT;                         // 136 MiB
static constexpr size_t SZ_PART=(size_t)NBH*NCHUNK*256*80*4;       // 40 MiB
static constexpr size_t O_CTXT=O_PART+SZ_PART;                     // 176 MiB
static constexpr size_t SZ_CTXT=(size_t)NBH*64*NBFX*2;
static constexpr size_t O_KSUM=O_CTXT+SZ_CTXT;
static constexpr size_t SZ_KSUM=(size_t)NBH*NBFX*4;
static constexpr size_t O_MAX=O_KSUM+SZ_KSUM;
static constexpr size_t SZ_MAX=(size_t)NBH*128*4;
static constexpr size_t O_VSUM=O_MAX+SZ_MAX;
static constexpr size_t SZ_VSUM=(size_t)NBH*80*4;
static constexpr size_t O_CS=O_VSUM+SZ_VSUM;
static constexpr size_t SZ_CS=(size_t)NBH*80*4;
static constexpr size_t O_WQKV=O_CS+SZ_CS;
static constexpr size_t SZ_WQKV=(size_t)2*1536*DIMX*2;             // 3 MiB
static constexpr size_t O_WOT=O_WQKV+SZ_WQKV;
static constexpr size_t SZ_W=(size_t)2*DIMX*DIMX*2;                // 1 MiB
static constexpr size_t O_W1T=O_WOT+SZ_W;
static constexpr size_t SZ_W1=(size_t)2*FFD*DIMX*2;                // 4 MiB
static constexpr size_t O_W2T=O_W1T+SZ_W1;
static constexpr size_t O_PJ=O_W2T+SZ_W1;
static constexpr size_t O_QKVB=O_PJ+(size_t)2*NBFX*DHEAD*2;
static constexpr size_t WS_END=O_QKVB+(size_t)2*1536*4;

extern "C" void kernel_launch(void* const* d_in, const int* in_sizes, int n_in,
                              void* d_out, int out_size, void* d_ws, size_t ws_size,
                              hipStream_t stream){
  (void)in_sizes;(void)n_in;(void)out_size;
  const float* xin =(const float*)d_in[0];
  const float* ln1g=(const float*)d_in[1];
  const float* ln1b=(const float*)d_in[2];
  const float* ln2g=(const float*)d_in[3];
  const float* ln2b=(const float*)d_in[4];
  const float* Wq=(const float*)d_in[5];
  const float* bq=(const float*)d_in[6];
  const float* Wk=(const float*)d_in[7];
  const float* bk=(const float*)d_in[8];
  const float* Wv=(const float*)d_in[9];
  const float* bv=(const float*)d_in[10];
  const float* Wo=(const float*)d_in[11];
  const float* bo=(const float*)d_in[12];
  const float* proj=(const float*)d_in[13];
  const float* W1=(const float*)d_in[14];
  const float* b1=(const float*)d_in[15];
  const float* W2=(const float*)d_in[16];
  const float* b2=(const float*)d_in[17];
  float* xout=(float*)d_out;

  copy_f32<<<(TOK*DIMX/4)/256,256,0,stream>>>((const float4*)xin,(float4*)xout, TOK*DIMX/4);
  if(ws_size < WS_END) return;

  char* ws=(char*)d_ws;
  u16* ybuf =(u16*)(ws+O_Y);
  u16* qbuf =(u16*)(ws+O_Q);
  u16* kbuf =(u16*)(ws+O_K);
  u16* vtb  =(u16*)(ws+O_VT);
  float* partb=(float*)(ws+O_PART);
  u16* ctxtb=(u16*)(ws+O_CTXT);
  float* ksumb=(float*)(ws+O_KSUM);
  float* maxb=(float*)(ws+O_MAX);
  float* vsumb=(float*)(ws+O_VSUM);
  float* csb=(float*)(ws+O_CS);
  u16* wqkvt=(u16*)(ws+O_WQKV);
  u16* wot=(u16*)(ws+O_WOT);
  u16* w1t=(u16*)(ws+O_W1T); u16* w2t=(u16*)(ws+O_W2T);
  u16* pjb=(u16*)(ws+O_PJ);
  float* qkvb=(float*)(ws+O_QKVB);
  u16* hbuf=(u16*)(ws+O_Q);   // FF hidden [32768][2048] reuses q/k/vt/part regions

  for(int l=0;l<2;l++){
    size_t wo=(size_t)l*DIMX*DIMX;
    convT<<<dim3(16,16),dim3(32,8),0,stream>>>(Wq+wo, wqkvt+(size_t)(l*1536+   0)*DIMX, DIMX, DIMX);
    convT<<<dim3(16,16),dim3(32,8),0,stream>>>(Wk+wo, wqkvt+(size_t)(l*1536+ 512)*DIMX, DIMX, DIMX);
    convT<<<dim3(16,16),dim3(32,8),0,stream>>>(Wv+wo, wqkvt+(size_t)(l*1536+1024)*DIMX, DIMX, DIMX);
    convT<<<dim3(16,16),dim3(32,8),0,stream>>>(Wo+wo, wot+wo, DIMX, DIMX);
    size_t w1o=(size_t)l*DIMX*FFD;
    convT<<<dim3(64,16),dim3(32,8),0,stream>>>(W1+w1o, w1t+w1o, DIMX, FFD);
    convT<<<dim3(16,64),dim3(32,8),0,stream>>>(W2+w1o, w2t+w1o, FFD, DIMX);
  }
  conv_proj<<<(2*NBFX*DHEAD)/256,256,0,stream>>>(proj, pjb, 2*NBFX*DHEAD);
  pack_bias<<<12,256,0,stream>>>(bq,bk,bv,qkvb);

  for(int l=0;l<2;l++){
    const u16* wqkvt_l=wqkvt+(size_t)l*1536*DIMX;
    const u16* wot_l=wot+(size_t)l*DIMX*DIMX;
    const u16* w1t_l=w1t+(size_t)l*DIMX*FFD;
    const u16* w2t_l=w2t+(size_t)l*DIMX*FFD;
    const u16* pj_l =pjb+(size_t)l*NBFX*DHEAD;
    const float* qkvb_l=qkvb+(size_t)l*1536;

    ln_k<<<TOK/4,256,0,stream>>>(xout, ln1g+l*DIMX, ln1b+l*DIMX, ybuf);
    fill_vt<<<(NBH*16*SEQ)/256,256,0,stream>>>(vtb);
    gemm256<0,512><<<dim3(6,128),512,0,stream>>>(ybuf, wqkvt_l, qkvb_l, qbuf, vtb, 1536);
    vsum_k<<<520,256,0,stream>>>(vtb, vsumb);
    kctx<<<dim3(NCHUNK,2,32),256,0,stream>>>(kbuf, pj_l, vtb, partb, maxb);
    ctx_reduce<<<dim3(8,32),256,0,stream>>>(partb, maxb, vsumb, ctxtb, ksumb);
    csum_k<<<32,256,0,stream>>>(ctxtb, ksumb, csb);
    q_fused<<<dim3(128,32),256,0,stream>>>(qbuf, pj_l, ctxtb, ksumb, csb, ybuf);
    gemm256<1,512><<<dim3(2,128),512,0,stream>>>(ybuf, wot_l, bo+l*DIMX, xout, nullptr, DIMX);
    ln_k<<<TOK/4,256,0,stream>>>(xout, ln2g+l*DIMX, ln2b+l*DIMX, ybuf);
    gemm256<2,512><<<dim3(8,128),512,0,stream>>>(ybuf, w1t_l, b1+l*FFD, hbuf, nullptr, FFD);
    gemm256<1,2048><<<dim3(2,128),512,0,stream>>>(hbuf, w2t_l, b2+l*DIMX, xout, nullptr, DIMX);
  }
}